// Round 4
// baseline (512.804 us; speedup 1.0000x reference)
//
#include <hip/hip_runtime.h>
#include <cstddef>

#define CAPD 64
#define BSZ 512      // nodes per bucket
#define BSH 9        // log2(BSZ)
#define CHUNK 8192   // edges per partition block

// ---------- fill pipeline: counting-sort partition by dst bucket ----------
// Requires: N <= 2^23 (src packed in 23 bits), buckets = ceil(N/512) <= 256.

// Phase 1: per-(block,bucket) histogram. gHist layout [bucket][NB2] (bucket-major).
__global__ __launch_bounds__(256) void p1_count(const int* __restrict__ edst, int E,
                                                int nb, int NB2, int* __restrict__ gHist) {
    __shared__ int hist[256];
    int bid = blockIdx.x, tid = threadIdx.x;
    hist[tid] = 0;
    __syncthreads();
    int e0 = bid * CHUNK, e1 = min(E, e0 + CHUNK);
    for (int e = e0 + tid; e < e1; e += 256)
        atomicAdd(&hist[edst[e] >> BSH], 1);
    __syncthreads();
    for (int i = tid; i < nb; i += 256)
        gHist[i * NB2 + bid] = hist[i];
}

// Phase 2: offsets. gStart[b][j] = bucketBase[b] + prefix of gHist[b][0..j).
__global__ __launch_bounds__(256) void p2_scan(const int* __restrict__ gHist,
                                               int* __restrict__ gStart,
                                               int nb, int NB2, int* __restrict__ bucketBase) {
    __shared__ int tot[256];
    __shared__ int sc[256];
    int t = threadIdx.x;
    int sum = 0;
    if (t < nb) {
        for (int j = 0; j < NB2; ++j) {
            gStart[t * NB2 + j] = sum;
            sum += gHist[t * NB2 + j];
        }
    }
    tot[t] = (t < nb) ? sum : 0;
    __syncthreads();
    sc[t] = tot[t];
    __syncthreads();
    for (int off = 1; off < 256; off <<= 1) {
        int v = (t >= off) ? sc[t - off] : 0;
        __syncthreads();
        sc[t] += v;
        __syncthreads();
    }
    int base = sc[t] - tot[t];  // exclusive prefix of bucket totals
    if (t < nb) {
        for (int j = 0; j < NB2; ++j) gStart[t * NB2 + j] += base;
        bucketBase[t] = base;
        if (t == nb - 1) bucketBase[nb] = base + tot[t];
    }
}

// Phase 3: counting-sort each chunk in LDS, write bucket segments semi-coalesced.
__global__ __launch_bounds__(256) void p3_scatter(const int* __restrict__ esrc,
                                                  const int* __restrict__ edst, int E,
                                                  int nb, int NB2,
                                                  const int* __restrict__ gStart,
                                                  unsigned* __restrict__ gSorted) {
    __shared__ unsigned lds[CHUNK];  // 32KB
    __shared__ int hist[256], segoff[256], cursor[256], gbase[256], sc[256];
    int bid = blockIdx.x, tid = threadIdx.x;
    int e0 = bid * CHUNK, e1 = min(E, e0 + CHUNK);
    hist[tid] = 0;
    __syncthreads();
    for (int e = e0 + tid; e < e1; e += 256)
        atomicAdd(&hist[edst[e] >> BSH], 1);
    __syncthreads();
    sc[tid] = hist[tid];
    __syncthreads();
    for (int off = 1; off < 256; off <<= 1) {
        int v = (tid >= off) ? sc[tid - off] : 0;
        __syncthreads();
        sc[tid] += v;
        __syncthreads();
    }
    segoff[tid] = sc[tid] - hist[tid];
    cursor[tid] = segoff[tid];
    if (tid < nb) gbase[tid] = gStart[tid * NB2 + bid];
    __syncthreads();
    for (int e = e0 + tid; e < e1; e += 256) {
        int d = edst[e];
        int b = d >> BSH;
        int p = atomicAdd(&cursor[b], 1);
        lds[p] = (unsigned)esrc[e] | ((unsigned)(d & (BSZ - 1)) << 23);
    }
    __syncthreads();
    int wave = tid >> 6, lane = tid & 63;
    for (int b = wave; b < nb; b += 4) {
        int off = segoff[b], len = hist[b], gb = gbase[b];
        for (int i = lane; i < len; i += 64)
            gSorted[gb + i] = lds[off + i];
    }
}

// Phase 4: one block per bucket. Build ELL fully in LDS, stream out coalesced.
// Also emits cnt (true in-degree) and isd = rsqrt(1+cnt).
__global__ __launch_bounds__(256) void p4_build(const unsigned* __restrict__ gSorted,
                                                const int* __restrict__ bucketBase,
                                                int N, int* __restrict__ cnt,
                                                float* __restrict__ isd,
                                                int* __restrict__ ell) {
    __shared__ unsigned ellL[BSZ * CAPD];  // 128KB
    __shared__ int cntL[BSZ];
    int b = blockIdx.x, tid = threadIdx.x;
    int n0 = b * BSZ;
    for (int i = tid; i < BSZ; i += 256) cntL[i] = 0;
    __syncthreads();
    int base = bucketBase[b], len = bucketBase[b + 1] - base;
    for (int i = tid; i < len; i += 256) {
        unsigned e = gSorted[base + i];
        int dl = (int)(e >> 23);
        int src = (int)(e & 0x7FFFFFu);
        int p = atomicAdd(&cntL[dl], 1);
        if (p < CAPD) ellL[dl * CAPD + p] = (unsigned)src;
    }
    __syncthreads();
    int nValid = min(BSZ, N - n0);
    int total = nValid * CAPD;
    const int* ellLi = (const int*)ellL;
    for (int i = tid; i < total; i += 256)
        ell[(size_t)n0 * CAPD + i] = ellLi[i];
    for (int i = tid; i < nValid; i += 256) {
        int c = cntL[i];
        cnt[n0 + i] = c;
        isd[n0 + i] = rsqrtf(1.0f + (float)c);
    }
}

// ---------- dense pipeline (unchanged from R3) ----------

// Tsc[N,128] = diag(scale) * (X[N,128] @ W[128,128]), f32 vector-ALU GEMM.
__global__ __launch_bounds__(256) void gemm128_kernel(const float* __restrict__ X,
                                                      const float* __restrict__ W,
                                                      const float* __restrict__ scale,
                                                      float* __restrict__ T, int n) {
    __shared__ float xs[32][132];
    __shared__ float ws[32][132];
    const int tid = threadIdx.x;
    const int tx = tid & 15;
    const int ty = tid >> 4;
    const int m0 = blockIdx.x * 128;
    float acc[8][8];
#pragma unroll
    for (int i = 0; i < 8; ++i)
#pragma unroll
        for (int j = 0; j < 8; ++j) acc[i][j] = 0.f;

    const int xr = tid >> 3;
    const int xc = (tid & 7) << 2;
    const int wr = tid >> 5;
    const int wc = (tid & 31) << 2;

    for (int k0 = 0; k0 < 128; k0 += 32) {
#pragma unroll
        for (int p = 0; p < 4; ++p) {
            int m = xr + p * 32;
            int row = m0 + m;
            float4 v = make_float4(0.f, 0.f, 0.f, 0.f);
            if (row < n) v = *reinterpret_cast<const float4*>(X + (size_t)row * 128 + k0 + xc);
            xs[xc + 0][m] = v.x; xs[xc + 1][m] = v.y;
            xs[xc + 2][m] = v.z; xs[xc + 3][m] = v.w;
        }
#pragma unroll
        for (int p = 0; p < 4; ++p) {
            int k = wr + p * 8;
            float4 v = *reinterpret_cast<const float4*>(W + (size_t)(k0 + k) * 128 + wc);
            *reinterpret_cast<float4*>(&ws[k][wc]) = v;
        }
        __syncthreads();
#pragma unroll
        for (int k = 0; k < 32; ++k) {
            float a[8], bb[8];
            *reinterpret_cast<float4*>(&a[0]) = *reinterpret_cast<const float4*>(&xs[k][ty * 8]);
            *reinterpret_cast<float4*>(&a[4]) = *reinterpret_cast<const float4*>(&xs[k][ty * 8 + 4]);
            *reinterpret_cast<float4*>(&bb[0]) = *reinterpret_cast<const float4*>(&ws[k][tx * 8]);
            *reinterpret_cast<float4*>(&bb[4]) = *reinterpret_cast<const float4*>(&ws[k][tx * 8 + 4]);
#pragma unroll
            for (int i = 0; i < 8; ++i)
#pragma unroll
                for (int j = 0; j < 8; ++j)
                    acc[i][j] = fmaf(a[i], bb[j], acc[i][j]);
        }
        __syncthreads();
    }
#pragma unroll
    for (int i = 0; i < 8; ++i) {
        int row = m0 + ty * 8 + i;
        if (row < n) {
            float s = scale[row];
            float4 v0 = make_float4(s * acc[i][0], s * acc[i][1], s * acc[i][2], s * acc[i][3]);
            float4 v1 = make_float4(s * acc[i][4], s * acc[i][5], s * acc[i][6], s * acc[i][7]);
            *reinterpret_cast<float4*>(T + (size_t)row * 128 + tx * 8) = v0;
            *reinterpret_cast<float4*>(T + (size_t)row * 128 + tx * 8 + 4) = v1;
        }
    }
}

// One wave per node. Tsc pre-scaled by isd[src]:
//   H[i] = relu( isd[i] * (Tsc[i] + sum_j Tsc[src_j]) + bias )
__global__ __launch_bounds__(256) void agg_kernel(const float* __restrict__ Tsc,
                                                  const int* __restrict__ ell,
                                                  const int* __restrict__ cnt,
                                                  const float* __restrict__ isd,
                                                  const float* __restrict__ bias,
                                                  float* __restrict__ H, int n) {
    int gw = (int)((blockIdx.x * 256 + threadIdx.x) >> 6);
    int lane = threadIdx.x & 63;
    if (gw >= n) return;
    float di = isd[gw];
    int c = cnt[gw];
    if (c > CAPD) c = CAPD;
    const int* row = ell + (size_t)gw * CAPD;
    float acc0 = Tsc[(size_t)gw * 128 + lane];
    float acc1 = Tsc[(size_t)gw * 128 + 64 + lane];
    int j = 0;
    for (; j + 4 <= c; j += 4) {
        int4 s4 = *reinterpret_cast<const int4*>(row + j);
        const float* p0 = Tsc + (size_t)s4.x * 128;
        const float* p1 = Tsc + (size_t)s4.y * 128;
        const float* p2 = Tsc + (size_t)s4.z * 128;
        const float* p3 = Tsc + (size_t)s4.w * 128;
        float a0 = p0[lane],      a1 = p1[lane],      a2 = p2[lane],      a3 = p3[lane];
        float b0 = p0[lane + 64], b1 = p1[lane + 64], b2 = p2[lane + 64], b3 = p3[lane + 64];
        acc0 += (a0 + a1) + (a2 + a3);
        acc1 += (b0 + b1) + (b2 + b3);
    }
    for (; j < c; ++j) {
        int s = row[j];
        acc0 += Tsc[(size_t)s * 128 + lane];
        acc1 += Tsc[(size_t)s * 128 + 64 + lane];
    }
    H[(size_t)gw * 128 + lane]      = fmaxf(fmaf(di, acc0, bias[lane]), 0.f);
    H[(size_t)gw * 128 + lane + 64] = fmaxf(fmaf(di, acc1, bias[lane + 64]), 0.f);
}

// One wave per node: out[i] = sigmoid( dot(H[i], Wout) + bout )
__global__ __launch_bounds__(256) void out_kernel(const float* __restrict__ H,
                                                  const float* __restrict__ Wout,
                                                  const float* __restrict__ bout,
                                                  float* __restrict__ out, int n) {
    int gw = (int)((blockIdx.x * 256 + threadIdx.x) >> 6);
    int lane = threadIdx.x & 63;
    if (gw >= n) return;
    float v = fmaf(H[(size_t)gw * 128 + lane], Wout[lane],
                   H[(size_t)gw * 128 + lane + 64] * Wout[lane + 64]);
#pragma unroll
    for (int off = 32; off > 0; off >>= 1) v += __shfl_xor(v, off, 64);
    if (lane == 0) out[gw] = 1.f / (1.f + expf(-(v + bout[0])));
}

extern "C" void kernel_launch(void* const* d_in, const int* in_sizes, int n_in,
                              void* d_out, int out_size, void* d_ws, size_t ws_size,
                              hipStream_t stream) {
    const float* x    = (const float*)d_in[0];
    const int*   ei   = (const int*)d_in[1];   // [2, E] int32 (JAX demotes int64)
    const float* W1   = (const float*)d_in[2];
    const float* b1   = (const float*)d_in[3];
    const float* W2   = (const float*)d_in[4];
    const float* b2   = (const float*)d_in[5];
    const float* Wout = (const float*)d_in[6];
    const float* bout = (const float*)d_in[7];
    float* out = (float*)d_out;

    const int N = in_sizes[0] / 128;
    const int E = in_sizes[1] / 2;
    const int* esrc = ei;
    const int* edst = ei + E;

    char* p = (char*)d_ws;
    auto alloc = [&](size_t bytes) {
        char* r = p;
        p += (bytes + 255) & ~(size_t)255;
        return (void*)r;
    };
    int*   cnt = (int*)  alloc((size_t)N * 4);
    float* isd = (float*)alloc((size_t)N * 4);
    int*   ell = (int*)  alloc((size_t)N * CAPD * 4);
    float* T   = (float*)alloc((size_t)N * 128 * 4);
    float* H   = (float*)alloc((size_t)N * 128 * 4);

    // Fill-pipeline scratch aliases the T region (T not live until gemm).
    const int nb  = (N + BSZ - 1) / BSZ;       // buckets (<=256 for N<=128K)
    const int NB2 = (E + CHUNK - 1) / CHUNK;   // partition blocks
    char* q = (char*)T;
    auto alloc2 = [&](size_t bytes) {
        char* r = q;
        q += (bytes + 255) & ~(size_t)255;
        return (void*)r;
    };
    unsigned* gSorted    = (unsigned*)alloc2((size_t)E * 4);
    int*      gHist      = (int*)     alloc2((size_t)nb * NB2 * 4);
    int*      gStart     = (int*)     alloc2((size_t)nb * NB2 * 4);
    int*      bucketBase = (int*)     alloc2((size_t)(nb + 1) * 4);

    p1_count  <<<NB2, 256, 0, stream>>>(edst, E, nb, NB2, gHist);
    p2_scan   <<<1,   256, 0, stream>>>(gHist, gStart, nb, NB2, bucketBase);
    p3_scatter<<<NB2, 256, 0, stream>>>(esrc, edst, E, nb, NB2, gStart, gSorted);
    p4_build  <<<nb,  256, 0, stream>>>(gSorted, bucketBase, N, cnt, isd, ell);

    // Layer 1: T = diag(isd)*(x@W1) ; H = relu(isd*(T_self + sum T_src) + b1)
    gemm128_kernel<<<(N + 127) / 128, 256, 0, stream>>>(x, W1, isd, T, N);
    agg_kernel<<<(N + 3) / 4, 256, 0, stream>>>(T, ell, cnt, isd, b1, H, N);

    // Layer 2 (agg reads only T -> overwriting H is safe)
    gemm128_kernel<<<(N + 127) / 128, 256, 0, stream>>>(H, W2, isd, T, N);
    agg_kernel<<<(N + 3) / 4, 256, 0, stream>>>(T, ell, cnt, isd, b2, H, N);

    // Output head
    out_kernel<<<(N + 3) / 4, 256, 0, stream>>>(H, Wout, bout, out, N);
}

// Round 5
// 393.128 us; speedup vs baseline: 1.3044x; 1.3044x over previous
//
#include <hip/hip_runtime.h>
#include <cstddef>

#define CAPD 64
#define BSZ 512      // nodes per bucket
#define BSH 9        // log2(BSZ)
#define CHUNK 8192   // edges per partition block

typedef unsigned int uint;

// bf16 helpers: word = dimEven | dimOdd<<16 (little-endian pair)
__device__ inline float bf_lo(uint v) { union { uint u; float f; } c; c.u = v << 16; return c.f; }
__device__ inline float bf_hi(uint v) { union { uint u; float f; } c; c.u = v & 0xFFFF0000u; return c.f; }
__device__ inline uint bf_pack(float a, float b) {
    union { float f; uint u; } x, y;
    x.f = a; y.f = b;
    uint ta = (x.u + 0x7FFFu + ((x.u >> 16) & 1u)) >> 16;
    uint tb = (y.u + 0x7FFFu + ((y.u >> 16) & 1u)) & 0xFFFF0000u;
    return ta | tb;
}

// ---------- fill pipeline: counting-sort partition by dst bucket ----------
// gHist/gStart layout: [chunkblock][bucket] -> all accesses coalesced.

__global__ __launch_bounds__(256) void p1_count(const int* __restrict__ edst, int E,
                                                int nb, int* __restrict__ gHist) {
    __shared__ int hist[256];
    int bid = blockIdx.x, tid = threadIdx.x;
    hist[tid] = 0;
    __syncthreads();
    int e0 = bid * CHUNK, e1 = min(E, e0 + CHUNK);
    for (int e = e0 + tid; e < e1; e += 256)
        atomicAdd(&hist[edst[e] >> BSH], 1);
    __syncthreads();
    for (int i = tid; i < nb; i += 256)
        gHist[bid * nb + i] = hist[i];
}

// Phase 2: gStart[j][b] = bucketBase[b] + prefix over chunks 0..j of gHist[.][b].
// Two coalesced passes; single block, one thread per bucket.
__global__ __launch_bounds__(256) void p2_scan(const int* __restrict__ gHist,
                                               int* __restrict__ gStart,
                                               int nb, int NB2, int* __restrict__ bucketBase) {
    __shared__ int tot[256];
    __shared__ int sc[256];
    int t = threadIdx.x;
    int sum = 0;
    if (t < nb)
        for (int j = 0; j < NB2; ++j) sum += gHist[j * nb + t];
    tot[t] = (t < nb) ? sum : 0;
    __syncthreads();
    sc[t] = tot[t];
    __syncthreads();
    for (int off = 1; off < 256; off <<= 1) {
        int v = (t >= off) ? sc[t - off] : 0;
        __syncthreads();
        sc[t] += v;
        __syncthreads();
    }
    int base = sc[t] - tot[t];  // exclusive prefix of bucket totals
    if (t < nb) {
        int run = base;
        for (int j = 0; j < NB2; ++j) {
            gStart[j * nb + t] = run;
            run += gHist[j * nb + t];
        }
        bucketBase[t] = base;
        if (t == nb - 1) bucketBase[nb] = base + tot[t];
    }
}

// Phase 3: counting-sort each chunk in LDS, write bucket segments coalesced.
__global__ __launch_bounds__(256) void p3_scatter(const int* __restrict__ esrc,
                                                  const int* __restrict__ edst, int E,
                                                  int nb,
                                                  const int* __restrict__ gStart,
                                                  unsigned* __restrict__ gSorted) {
    __shared__ unsigned lds[CHUNK];  // 32KB
    __shared__ int hist[256], segoff[256], cursor[256], gbase[256], sc[256];
    int bid = blockIdx.x, tid = threadIdx.x;
    int e0 = bid * CHUNK, e1 = min(E, e0 + CHUNK);
    hist[tid] = 0;
    __syncthreads();
    for (int e = e0 + tid; e < e1; e += 256)
        atomicAdd(&hist[edst[e] >> BSH], 1);
    __syncthreads();
    sc[tid] = hist[tid];
    __syncthreads();
    for (int off = 1; off < 256; off <<= 1) {
        int v = (tid >= off) ? sc[tid - off] : 0;
        __syncthreads();
        sc[tid] += v;
        __syncthreads();
    }
    segoff[tid] = sc[tid] - hist[tid];
    cursor[tid] = segoff[tid];
    if (tid < nb) gbase[tid] = gStart[bid * nb + tid];
    __syncthreads();
    for (int e = e0 + tid; e < e1; e += 256) {
        int d = edst[e];
        int b = d >> BSH;
        int p = atomicAdd(&cursor[b], 1);
        lds[p] = (unsigned)esrc[e] | ((unsigned)(d & (BSZ - 1)) << 23);
    }
    __syncthreads();
    int wave = tid >> 6, lane = tid & 63;
    for (int b = wave; b < nb; b += 4) {
        int off = segoff[b], len = hist[b], gb = gbase[b];
        for (int i = lane; i < len; i += 64)
            gSorted[gb + i] = lds[off + i];
    }
}

// Phase 4: one block per bucket. Build ELL fully in LDS, stream out coalesced.
// Also emits cnt (true in-degree) and isd = rsqrt(1+cnt).
__global__ __launch_bounds__(256) void p4_build(const unsigned* __restrict__ gSorted,
                                                const int* __restrict__ bucketBase,
                                                int N, int* __restrict__ cnt,
                                                float* __restrict__ isd,
                                                int* __restrict__ ell) {
    __shared__ unsigned ellL[BSZ * CAPD];  // 128KB
    __shared__ int cntL[BSZ];
    int b = blockIdx.x, tid = threadIdx.x;
    int n0 = b * BSZ;
    for (int i = tid; i < BSZ; i += 256) cntL[i] = 0;
    __syncthreads();
    int base = bucketBase[b], len = bucketBase[b + 1] - base;
    for (int i = tid; i < len; i += 256) {
        unsigned e = gSorted[base + i];
        int dl = (int)(e >> 23);
        int src = (int)(e & 0x7FFFFFu);
        int p = atomicAdd(&cntL[dl], 1);
        if (p < CAPD) ellL[dl * CAPD + p] = (unsigned)src;
    }
    __syncthreads();
    int nValid = min(BSZ, N - n0);
    int total = nValid * CAPD;
    const int* ellLi = (const int*)ellL;
    for (int i = tid; i < total; i += 256)
        ell[(size_t)n0 * CAPD + i] = ellLi[i];
    for (int i = tid; i < nValid; i += 256) {
        int c = cntL[i];
        cnt[n0 + i] = c;
        isd[n0 + i] = rsqrtf(1.0f + (float)c);
    }
}

// ---------- dense pipeline ----------

// Tsc[N,128](bf16) = diag(scale) * (X[N,128] @ W[128,128]); f32 compute, bf16 store.
__global__ __launch_bounds__(256) void gemm128_kernel(const float* __restrict__ X,
                                                      const float* __restrict__ W,
                                                      const float* __restrict__ scale,
                                                      uint* __restrict__ Tb,  // N x 64 words
                                                      int n) {
    __shared__ float xs[32][132];
    __shared__ float ws[32][132];
    const int tid = threadIdx.x;
    const int tx = tid & 15;
    const int ty = tid >> 4;
    const int m0 = blockIdx.x * 128;
    float acc[8][8];
#pragma unroll
    for (int i = 0; i < 8; ++i)
#pragma unroll
        for (int j = 0; j < 8; ++j) acc[i][j] = 0.f;

    const int xr = tid >> 3;
    const int xc = (tid & 7) << 2;
    const int wr = tid >> 5;
    const int wc = (tid & 31) << 2;

    for (int k0 = 0; k0 < 128; k0 += 32) {
#pragma unroll
        for (int p = 0; p < 4; ++p) {
            int m = xr + p * 32;
            int row = m0 + m;
            float4 v = make_float4(0.f, 0.f, 0.f, 0.f);
            if (row < n) v = *reinterpret_cast<const float4*>(X + (size_t)row * 128 + k0 + xc);
            xs[xc + 0][m] = v.x; xs[xc + 1][m] = v.y;
            xs[xc + 2][m] = v.z; xs[xc + 3][m] = v.w;
        }
#pragma unroll
        for (int p = 0; p < 4; ++p) {
            int k = wr + p * 8;
            float4 v = *reinterpret_cast<const float4*>(W + (size_t)(k0 + k) * 128 + wc);
            *reinterpret_cast<float4*>(&ws[k][wc]) = v;
        }
        __syncthreads();
#pragma unroll
        for (int k = 0; k < 32; ++k) {
            float a[8], bb[8];
            *reinterpret_cast<float4*>(&a[0]) = *reinterpret_cast<const float4*>(&xs[k][ty * 8]);
            *reinterpret_cast<float4*>(&a[4]) = *reinterpret_cast<const float4*>(&xs[k][ty * 8 + 4]);
            *reinterpret_cast<float4*>(&bb[0]) = *reinterpret_cast<const float4*>(&ws[k][tx * 8]);
            *reinterpret_cast<float4*>(&bb[4]) = *reinterpret_cast<const float4*>(&ws[k][tx * 8 + 4]);
#pragma unroll
            for (int i = 0; i < 8; ++i)
#pragma unroll
                for (int j = 0; j < 8; ++j)
                    acc[i][j] = fmaf(a[i], bb[j], acc[i][j]);
        }
        __syncthreads();
    }
#pragma unroll
    for (int i = 0; i < 8; ++i) {
        int row = m0 + ty * 8 + i;
        if (row < n) {
            float s = scale[row];
            uint4 v;
            v.x = bf_pack(s * acc[i][0], s * acc[i][1]);
            v.y = bf_pack(s * acc[i][2], s * acc[i][3]);
            v.z = bf_pack(s * acc[i][4], s * acc[i][5]);
            v.w = bf_pack(s * acc[i][6], s * acc[i][7]);
            *reinterpret_cast<uint4*>(Tb + (size_t)row * 64 + tx * 4) = v;
        }
    }
}

// One wave per node, bf16 rows (one 256B wave-load per row):
//   H[i] = relu( isd[i] * (Tsc[i] + sum_j Tsc[src_j]) + bias )
// Lane l handles dims 2l, 2l+1. Unroll x8 -> 8 row loads in flight.
__global__ __launch_bounds__(256) void agg_kernel(const uint* __restrict__ Tb,
                                                  const int* __restrict__ ell,
                                                  const int* __restrict__ cnt,
                                                  const float* __restrict__ isd,
                                                  const float* __restrict__ bias,
                                                  float* __restrict__ H, int n) {
    int gw = (int)((blockIdx.x * 256 + threadIdx.x) >> 6);
    int lane = threadIdx.x & 63;
    if (gw >= n) return;
    float di = isd[gw];
    int c = cnt[gw];
    if (c > CAPD) c = CAPD;
    const int* row = ell + (size_t)gw * CAPD;
    uint sv = Tb[(size_t)gw * 64 + lane];
    float acc0 = bf_lo(sv), acc1 = bf_hi(sv);
    int j = 0;
    for (; j + 8 <= c; j += 8) {
        int4 sa = *reinterpret_cast<const int4*>(row + j);
        int4 sb = *reinterpret_cast<const int4*>(row + j + 4);
        uint v0 = Tb[(size_t)sa.x * 64 + lane];
        uint v1 = Tb[(size_t)sa.y * 64 + lane];
        uint v2 = Tb[(size_t)sa.z * 64 + lane];
        uint v3 = Tb[(size_t)sa.w * 64 + lane];
        uint v4 = Tb[(size_t)sb.x * 64 + lane];
        uint v5 = Tb[(size_t)sb.y * 64 + lane];
        uint v6 = Tb[(size_t)sb.z * 64 + lane];
        uint v7 = Tb[(size_t)sb.w * 64 + lane];
        acc0 += ((bf_lo(v0) + bf_lo(v1)) + (bf_lo(v2) + bf_lo(v3))) +
                ((bf_lo(v4) + bf_lo(v5)) + (bf_lo(v6) + bf_lo(v7)));
        acc1 += ((bf_hi(v0) + bf_hi(v1)) + (bf_hi(v2) + bf_hi(v3))) +
                ((bf_hi(v4) + bf_hi(v5)) + (bf_hi(v6) + bf_hi(v7)));
    }
    for (; j + 4 <= c; j += 4) {
        int4 s4 = *reinterpret_cast<const int4*>(row + j);
        uint v0 = Tb[(size_t)s4.x * 64 + lane];
        uint v1 = Tb[(size_t)s4.y * 64 + lane];
        uint v2 = Tb[(size_t)s4.z * 64 + lane];
        uint v3 = Tb[(size_t)s4.w * 64 + lane];
        acc0 += (bf_lo(v0) + bf_lo(v1)) + (bf_lo(v2) + bf_lo(v3));
        acc1 += (bf_hi(v0) + bf_hi(v1)) + (bf_hi(v2) + bf_hi(v3));
    }
    for (; j < c; ++j) {
        uint v = Tb[(size_t)row[j] * 64 + lane];
        acc0 += bf_lo(v);
        acc1 += bf_hi(v);
    }
    float2 bv = *reinterpret_cast<const float2*>(bias + lane * 2);
    float h0 = fmaxf(fmaf(di, acc0, bv.x), 0.f);
    float h1 = fmaxf(fmaf(di, acc1, bv.y), 0.f);
    *reinterpret_cast<float2*>(H + (size_t)gw * 128 + lane * 2) = make_float2(h0, h1);
}

// One wave per node: out[i] = sigmoid( dot(H[i], Wout) + bout )
__global__ __launch_bounds__(256) void out_kernel(const float* __restrict__ H,
                                                  const float* __restrict__ Wout,
                                                  const float* __restrict__ bout,
                                                  float* __restrict__ out, int n) {
    int gw = (int)((blockIdx.x * 256 + threadIdx.x) >> 6);
    int lane = threadIdx.x & 63;
    if (gw >= n) return;
    float v = fmaf(H[(size_t)gw * 128 + lane], Wout[lane],
                   H[(size_t)gw * 128 + lane + 64] * Wout[lane + 64]);
#pragma unroll
    for (int off = 32; off > 0; off >>= 1) v += __shfl_xor(v, off, 64);
    if (lane == 0) out[gw] = 1.f / (1.f + expf(-(v + bout[0])));
}

extern "C" void kernel_launch(void* const* d_in, const int* in_sizes, int n_in,
                              void* d_out, int out_size, void* d_ws, size_t ws_size,
                              hipStream_t stream) {
    const float* x    = (const float*)d_in[0];
    const int*   ei   = (const int*)d_in[1];   // [2, E] int32 (JAX demotes int64)
    const float* W1   = (const float*)d_in[2];
    const float* b1   = (const float*)d_in[3];
    const float* W2   = (const float*)d_in[4];
    const float* b2   = (const float*)d_in[5];
    const float* Wout = (const float*)d_in[6];
    const float* bout = (const float*)d_in[7];
    float* out = (float*)d_out;

    const int N = in_sizes[0] / 128;
    const int E = in_sizes[1] / 2;
    const int* esrc = ei;
    const int* edst = ei + E;

    char* p = (char*)d_ws;
    auto alloc = [&](size_t bytes) {
        char* r = p;
        p += (bytes + 255) & ~(size_t)255;
        return (void*)r;
    };
    int*   cnt = (int*)  alloc((size_t)N * 4);
    float* isd = (float*)alloc((size_t)N * 4);
    int*   ell = (int*)  alloc((size_t)N * CAPD * 4);
    uint*  Tb  = (uint*) alloc((size_t)N * 64 * 4);   // N x 128 bf16
    float* H   = (float*)alloc((size_t)N * 128 * 4);

    // Fill-pipeline scratch aliases the Tb region (not live until gemm).
    const int nb  = (N + BSZ - 1) / BSZ;       // buckets (<=256 for N<=128K)
    const int NB2 = (E + CHUNK - 1) / CHUNK;   // partition blocks
    char* q = (char*)Tb;
    auto alloc2 = [&](size_t bytes) {
        char* r = q;
        q += (bytes + 255) & ~(size_t)255;
        return (void*)r;
    };
    unsigned* gSorted    = (unsigned*)alloc2((size_t)E * 4);
    int*      gHist      = (int*)     alloc2((size_t)nb * NB2 * 4);
    int*      gStart     = (int*)     alloc2((size_t)nb * NB2 * 4);
    int*      bucketBase = (int*)     alloc2((size_t)(nb + 1) * 4);

    p1_count  <<<NB2, 256, 0, stream>>>(edst, E, nb, gHist);
    p2_scan   <<<1,   256, 0, stream>>>(gHist, gStart, nb, NB2, bucketBase);
    p3_scatter<<<NB2, 256, 0, stream>>>(esrc, edst, E, nb, gStart, gSorted);
    p4_build  <<<nb,  256, 0, stream>>>(gSorted, bucketBase, N, cnt, isd, ell);

    // Layer 1: Tb = bf16(diag(isd)*(x@W1)) ; H = relu(isd*(Tb_self + sum Tb_src) + b1)
    gemm128_kernel<<<(N + 127) / 128, 256, 0, stream>>>(x, W1, isd, Tb, N);
    agg_kernel<<<(N + 3) / 4, 256, 0, stream>>>(Tb, ell, cnt, isd, b1, H, N);

    // Layer 2 (agg reads only Tb -> overwriting H is safe)
    gemm128_kernel<<<(N + 127) / 128, 256, 0, stream>>>(H, W2, isd, Tb, N);
    agg_kernel<<<(N + 3) / 4, 256, 0, stream>>>(Tb, ell, cnt, isd, b2, H, N);

    // Output head
    out_kernel<<<(N + 3) / 4, 256, 0, stream>>>(H, Wout, bout, out, N);
}

// Round 8
// 372.520 us; speedup vs baseline: 1.3766x; 1.0553x over previous
//
#include <hip/hip_runtime.h>
#include <cstddef>

#define CAPD 64
#define BSZ 512      // nodes per bucket
#define BSH 9        // log2(BSZ)
#define CHUNK 8192   // edges per partition block

typedef unsigned int uint;
typedef unsigned short ushort;
typedef float f32x4 __attribute__((ext_vector_type(4)));
typedef short bf16x8 __attribute__((ext_vector_type(8)));  // 8 bf16 = 4 VGPRs

// bf16 helpers: word = dimEven | dimOdd<<16
__device__ inline float bf_lo(uint v) { union { uint u; float f; } c; c.u = v << 16; return c.f; }
__device__ inline float bf_hi(uint v) { union { uint u; float f; } c; c.u = v & 0xFFFF0000u; return c.f; }
__device__ inline ushort bf_r(float x) {   // f32 -> bf16 RNE
    union { float f; uint u; } c; c.f = x;
    return (ushort)((c.u + 0x7FFFu + ((c.u >> 16) & 1u)) >> 16);
}
__device__ inline float bf_f(ushort h) {   // bf16 -> f32
    union { uint u; float f; } c; c.u = (uint)h << 16; return c.f;
}
__device__ inline uint bf_pack(float a, float b) {
    return (uint)bf_r(a) | ((uint)bf_r(b) << 16);
}

// ---------- fill pipeline: counting-sort partition by dst bucket ----------

__global__ __launch_bounds__(256) void p1_count(const int* __restrict__ edst, int E,
                                                int nb, int* __restrict__ gHist) {
    __shared__ int hist[256];
    int bid = blockIdx.x, tid = threadIdx.x;
    hist[tid] = 0;
    __syncthreads();
    int e0 = bid * CHUNK, e1 = min(E, e0 + CHUNK);
    for (int e = e0 + tid; e < e1; e += 256)
        atomicAdd(&hist[edst[e] >> BSH], 1);
    __syncthreads();
    for (int i = tid; i < nb; i += 256)
        gHist[bid * nb + i] = hist[i];
}

__global__ __launch_bounds__(256) void p2_scan(const int* __restrict__ gHist,
                                               int* __restrict__ gStart,
                                               int nb, int NB2, int* __restrict__ bucketBase) {
    __shared__ int tot[256];
    __shared__ int sc[256];
    int t = threadIdx.x;
    int sum = 0;
    if (t < nb)
        for (int j = 0; j < NB2; ++j) sum += gHist[j * nb + t];
    tot[t] = (t < nb) ? sum : 0;
    __syncthreads();
    sc[t] = tot[t];
    __syncthreads();
    for (int off = 1; off < 256; off <<= 1) {
        int v = (t >= off) ? sc[t - off] : 0;
        __syncthreads();
        sc[t] += v;
        __syncthreads();
    }
    int base = sc[t] - tot[t];
    if (t < nb) {
        int run = base;
        for (int j = 0; j < NB2; ++j) {
            gStart[j * nb + t] = run;
            run += gHist[j * nb + t];
        }
        bucketBase[t] = base;
        if (t == nb - 1) bucketBase[nb] = base + tot[t];
    }
}

__global__ __launch_bounds__(256) void p3_scatter(const int* __restrict__ esrc,
                                                  const int* __restrict__ edst, int E,
                                                  int nb,
                                                  const int* __restrict__ gStart,
                                                  unsigned* __restrict__ gSorted) {
    __shared__ unsigned lds[CHUNK];
    __shared__ int hist[256], segoff[256], cursor[256], gbase[256], sc[256];
    int bid = blockIdx.x, tid = threadIdx.x;
    int e0 = bid * CHUNK, e1 = min(E, e0 + CHUNK);
    hist[tid] = 0;
    __syncthreads();
    for (int e = e0 + tid; e < e1; e += 256)
        atomicAdd(&hist[edst[e] >> BSH], 1);
    __syncthreads();
    sc[tid] = hist[tid];
    __syncthreads();
    for (int off = 1; off < 256; off <<= 1) {
        int v = (tid >= off) ? sc[tid - off] : 0;
        __syncthreads();
        sc[tid] += v;
        __syncthreads();
    }
    segoff[tid] = sc[tid] - hist[tid];
    cursor[tid] = segoff[tid];
    if (tid < nb) gbase[tid] = gStart[bid * nb + tid];
    __syncthreads();
    for (int e = e0 + tid; e < e1; e += 256) {
        int d = edst[e];
        int b = d >> BSH;
        int p = atomicAdd(&cursor[b], 1);
        lds[p] = (unsigned)esrc[e] | ((unsigned)(d & (BSZ - 1)) << 23);
    }
    __syncthreads();
    int wave = tid >> 6, lane = tid & 63;
    for (int b = wave; b < nb; b += 4) {
        int off = segoff[b], len = hist[b], gb = gbase[b];
        for (int i = lane; i < len; i += 64)
            gSorted[gb + i] = lds[off + i];
    }
}

__global__ __launch_bounds__(256) void p4_build(const unsigned* __restrict__ gSorted,
                                                const int* __restrict__ bucketBase,
                                                int N, int* __restrict__ cnt,
                                                float* __restrict__ isd,
                                                int* __restrict__ ell) {
    __shared__ unsigned ellL[BSZ * CAPD];  // 128KB
    __shared__ int cntL[BSZ];
    int b = blockIdx.x, tid = threadIdx.x;
    int n0 = b * BSZ;
    for (int i = tid; i < BSZ; i += 256) cntL[i] = 0;
    __syncthreads();
    int base = bucketBase[b], len = bucketBase[b + 1] - base;
    for (int i = tid; i < len; i += 256) {
        unsigned e = gSorted[base + i];
        int dl = (int)(e >> 23);
        int src = (int)(e & 0x7FFFFFu);
        int p = atomicAdd(&cntL[dl], 1);
        if (p < CAPD) ellL[dl * CAPD + p] = (unsigned)src;
    }
    __syncthreads();
    int nValid = min(BSZ, N - n0);
    int total = nValid * CAPD;
    const int* ellLi = (const int*)ellL;
    for (int i = tid; i < total; i += 256)
        ell[(size_t)n0 * CAPD + i] = ellLi[i];
    for (int i = tid; i < nValid; i += 256) {
        int c = cntL[i];
        cnt[n0 + i] = c;
        isd[n0 + i] = rsqrtf(1.0f + (float)c);
    }
}

// ---------- W prep: W[128][128] f32 -> transposed split-bf16 hi/lo ----------
// Output layout: [col][64 kwords], word = k_even | k_odd<<16. grid=2 (W1, W2).
__global__ __launch_bounds__(256) void wtb_kernel(const float* __restrict__ Wa,
                                                  const float* __restrict__ Wb,
                                                  uint* __restrict__ OaHi, uint* __restrict__ OaLo,
                                                  uint* __restrict__ ObHi, uint* __restrict__ ObLo) {
    const float* W = blockIdx.x ? Wb : Wa;
    uint* OHi = blockIdx.x ? ObHi : OaHi;
    uint* OLo = blockIdx.x ? ObLo : OaLo;
    __shared__ float ws[128][129];
    int tid = threadIdx.x;
#pragma unroll
    for (int j = 0; j < 16; ++j) {
        int q = tid + 256 * j;          // 4096 float4 chunks
        int k = q >> 5, c = (q & 31) * 4;
        float4 v = *reinterpret_cast<const float4*>(W + k * 128 + c);
        ws[k][c] = v.x; ws[k][c + 1] = v.y; ws[k][c + 2] = v.z; ws[k][c + 3] = v.w;
    }
    __syncthreads();
#pragma unroll
    for (int j = 0; j < 32; ++j) {
        int q = tid + 256 * j;          // 8192 words
        int ncol = q >> 6, kw = q & 63;
        float w0 = ws[2 * kw][ncol], w1 = ws[2 * kw + 1][ncol];
        ushort h0 = bf_r(w0), h1 = bf_r(w1);
        ushort l0 = bf_r(w0 - bf_f(h0)), l1 = bf_r(w1 - bf_f(h1));
        OHi[q] = (uint)h0 | ((uint)h1 << 16);
        OLo[q] = (uint)l0 | ((uint)l1 << 16);
    }
}

// ---------- MFMA GEMM (bf16x3 split = f32-accurate): Tb = bf16(diag(scale)*(A @ W)) ----------
// A: f32 [n][128]. Whi/Wlo: [128 cols][64 kwords]. Block: 128x128, 4 waves.
// LDS 128KB: A_hi[0,32K) A_lo[32K,64K) W_hi[64K,96K) W_lo[96K,128K).
// Swizzle: byte ^= ((row&7)<<4) kills the 256B-stride bank conflict (G4/T2).
__global__ __launch_bounds__(256) void gemm_mfma(const float* __restrict__ A,
                                                 const uint* __restrict__ Whi,
                                                 const uint* __restrict__ Wlo,
                                                 const float* __restrict__ scale,
                                                 uint* __restrict__ Tb, int n) {
    __shared__ uint SH[32768];  // 128KB
    char* shb = (char*)SH;
    const int tid = threadIdx.x;
    const int m0 = blockIdx.x * 128;

    // Stage A: 128 rows x 128 f32 = 4096 x 16B chunks; split into hi/lo bf16.
#pragma unroll
    for (int j = 0; j < 16; ++j) {
        int q = tid + 256 * j;
        int row = q >> 5, c = q & 31;           // c: float4 chunk within row
        int grow = m0 + row;
        float4 v = make_float4(0.f, 0.f, 0.f, 0.f);
        if (grow < n) v = *reinterpret_cast<const float4*>(A + (size_t)grow * 128 + c * 4);
        ushort h0 = bf_r(v.x), h1 = bf_r(v.y), h2 = bf_r(v.z), h3 = bf_r(v.w);
        uint2 hi = make_uint2((uint)h0 | ((uint)h1 << 16), (uint)h2 | ((uint)h3 << 16));
        uint2 lo = make_uint2(
            (uint)bf_r(v.x - bf_f(h0)) | ((uint)bf_r(v.y - bf_f(h1)) << 16),
            (uint)bf_r(v.z - bf_f(h2)) | ((uint)bf_r(v.w - bf_f(h3)) << 16));
        int off = (c * 8) ^ ((row & 7) << 4);   // 8B-aligned, XOR on bits 4..6
        *reinterpret_cast<uint2*>(shb + row * 256 + off) = hi;
        *reinterpret_cast<uint2*>(shb + 32768 + row * 256 + off) = lo;
    }
    // Stage W hi/lo: each 128 cols x 256B = 2048 x 16B chunks.
#pragma unroll
    for (int j = 0; j < 8; ++j) {
        int q = tid + 256 * j;
        int col = q >> 4, c16 = q & 15;
        int off = (c16 * 16) ^ ((col & 7) << 4);
        uint4 vh = *reinterpret_cast<const uint4*>(Whi + col * 64 + c16 * 4);
        uint4 vl = *reinterpret_cast<const uint4*>(Wlo + col * 64 + c16 * 4);
        *reinterpret_cast<uint4*>(shb + 65536 + col * 256 + off) = vh;
        *reinterpret_cast<uint4*>(shb + 98304 + col * 256 + off) = vl;
    }
    __syncthreads();

    const int w = tid >> 6, l = tid & 63;
    const int lrow = l & 15, kg = l >> 4;
    const int swz = (lrow & 7) << 4;

    f32x4 acc[2][8] = {};
#pragma unroll
    for (int kk = 0; kk < 4; ++kk) {
        const int koff = (kk * 64 + kg * 16) ^ swz;
        bf16x8 ah[2], al[2], bh[8], bl[8];
#pragma unroll
        for (int mr = 0; mr < 2; ++mr) {
            int r = w * 32 + mr * 16 + lrow;
            ah[mr] = *reinterpret_cast<const bf16x8*>(shb + r * 256 + koff);
            al[mr] = *reinterpret_cast<const bf16x8*>(shb + 32768 + r * 256 + koff);
        }
#pragma unroll
        for (int nc = 0; nc < 8; ++nc) {
            int c = nc * 16 + lrow;
            bh[nc] = *reinterpret_cast<const bf16x8*>(shb + 65536 + c * 256 + koff);
            bl[nc] = *reinterpret_cast<const bf16x8*>(shb + 98304 + c * 256 + koff);
        }
#pragma unroll
        for (int mr = 0; mr < 2; ++mr)
#pragma unroll
            for (int nc = 0; nc < 8; ++nc) {
                acc[mr][nc] = __builtin_amdgcn_mfma_f32_16x16x32_bf16(ah[mr], bh[nc], acc[mr][nc], 0, 0, 0);
                acc[mr][nc] = __builtin_amdgcn_mfma_f32_16x16x32_bf16(ah[mr], bl[nc], acc[mr][nc], 0, 0, 0);
                acc[mr][nc] = __builtin_amdgcn_mfma_f32_16x16x32_bf16(al[mr], bh[nc], acc[mr][nc], 0, 0, 0);
            }
    }
    __syncthreads();  // tiles consumed; reuse LDS for epilogue transpose

    // C/D layout (m89): col = lane&15, row = (lane>>4)*4 + reg. Scale + pack via LDS.
    ushort* Cs = (ushort*)SH;   // [128][136] bf16 (pad breaks bank alignment)
#pragma unroll
    for (int mr = 0; mr < 2; ++mr) {
        int rb = w * 32 + mr * 16 + kg * 4;
#pragma unroll
        for (int i = 0; i < 4; ++i) {
            int grow = m0 + rb + i;
            float s = (grow < n) ? scale[grow] : 0.f;
#pragma unroll
            for (int nc = 0; nc < 8; ++nc)
                Cs[(rb + i) * 136 + nc * 16 + lrow] = bf_r(s * acc[mr][nc][i]);
        }
    }
    __syncthreads();
    const uint* Cw = (const uint*)SH;             // stride 68 words/row
#pragma unroll
    for (int j = 0; j < 8; ++j) {
        int q = tid + 256 * j;
        int row = q >> 4, c4 = q & 15;
        int grow = m0 + row;
        if (grow < n) {
            uint4 v = *reinterpret_cast<const uint4*>(Cw + row * 68 + c4 * 4);
            *reinterpret_cast<uint4*>(Tb + (size_t)grow * 64 + c4 * 4) = v;
        }
    }
}

// ---------- aggregation (bf16 gather in, f32 out) ----------
// H[i] = relu( isd[i] * (Tb[i] + sum_j Tb[src_j]) + bias ), lane l holds dims 2l,2l+1.
__global__ __launch_bounds__(256) void agg_kernel(const uint* __restrict__ Tb,
                                                  const int* __restrict__ ell,
                                                  const int* __restrict__ cnt,
                                                  const float* __restrict__ isd,
                                                  const float* __restrict__ bias,
                                                  float* __restrict__ H, int n) {
    int gw = (int)((blockIdx.x * 256 + threadIdx.x) >> 6);
    int lane = threadIdx.x & 63;
    if (gw >= n) return;
    float di = isd[gw];
    int c = cnt[gw];
    if (c > CAPD) c = CAPD;
    const int* row = ell + (size_t)gw * CAPD;
    uint sv = Tb[(size_t)gw * 64 + lane];
    float acc0 = bf_lo(sv), acc1 = bf_hi(sv);
    int j = 0;
    for (; j + 8 <= c; j += 8) {
        int4 sa = *reinterpret_cast<const int4*>(row + j);
        int4 sb = *reinterpret_cast<const int4*>(row + j + 4);
        uint v0 = Tb[(size_t)sa.x * 64 + lane];
        uint v1 = Tb[(size_t)sa.y * 64 + lane];
        uint v2 = Tb[(size_t)sa.z * 64 + lane];
        uint v3 = Tb[(size_t)sa.w * 64 + lane];
        uint v4 = Tb[(size_t)sb.x * 64 + lane];
        uint v5 = Tb[(size_t)sb.y * 64 + lane];
        uint v6 = Tb[(size_t)sb.z * 64 + lane];
        uint v7 = Tb[(size_t)sb.w * 64 + lane];
        acc0 += ((bf_lo(v0) + bf_lo(v1)) + (bf_lo(v2) + bf_lo(v3))) +
                ((bf_lo(v4) + bf_lo(v5)) + (bf_lo(v6) + bf_lo(v7)));
        acc1 += ((bf_hi(v0) + bf_hi(v1)) + (bf_hi(v2) + bf_hi(v3))) +
                ((bf_hi(v4) + bf_hi(v5)) + (bf_hi(v6) + bf_hi(v7)));
    }
    for (; j + 4 <= c; j += 4) {
        int4 s4 = *reinterpret_cast<const int4*>(row + j);
        uint v0 = Tb[(size_t)s4.x * 64 + lane];
        uint v1 = Tb[(size_t)s4.y * 64 + lane];
        uint v2 = Tb[(size_t)s4.z * 64 + lane];
        uint v3 = Tb[(size_t)s4.w * 64 + lane];
        acc0 += (bf_lo(v0) + bf_lo(v1)) + (bf_lo(v2) + bf_lo(v3));
        acc1 += (bf_hi(v0) + bf_hi(v1)) + (bf_hi(v2) + bf_hi(v3));
    }
    for (; j < c; ++j) {
        uint v = Tb[(size_t)row[j] * 64 + lane];
        acc0 += bf_lo(v);
        acc1 += bf_hi(v);
    }
    float2 bv = *reinterpret_cast<const float2*>(bias + lane * 2);
    float h0 = fmaxf(fmaf(di, acc0, bv.x), 0.f);
    float h1 = fmaxf(fmaf(di, acc1, bv.y), 0.f);
    *reinterpret_cast<float2*>(H + (size_t)gw * 128 + lane * 2) = make_float2(h0, h1);
}

// out[i] = sigmoid( dot(H[i], Wout) + bout ), H f32, lane l holds dims 2l,2l+1
__global__ __launch_bounds__(256) void out_kernel(const float* __restrict__ H,
                                                  const float* __restrict__ Wout,
                                                  const float* __restrict__ bout,
                                                  float* __restrict__ out, int n) {
    int gw = (int)((blockIdx.x * 256 + threadIdx.x) >> 6);
    int lane = threadIdx.x & 63;
    if (gw >= n) return;
    float2 hv = *reinterpret_cast<const float2*>(H + (size_t)gw * 128 + lane * 2);
    float2 wv = *reinterpret_cast<const float2*>(Wout + lane * 2);
    float v = fmaf(hv.x, wv.x, hv.y * wv.y);
#pragma unroll
    for (int off = 32; off > 0; off >>= 1) v += __shfl_xor(v, off, 64);
    if (lane == 0) out[gw] = 1.f / (1.f + expf(-(v + bout[0])));
}

extern "C" void kernel_launch(void* const* d_in, const int* in_sizes, int n_in,
                              void* d_out, int out_size, void* d_ws, size_t ws_size,
                              hipStream_t stream) {
    const float* x    = (const float*)d_in[0];
    const int*   ei   = (const int*)d_in[1];
    const float* W1   = (const float*)d_in[2];
    const float* b1   = (const float*)d_in[3];
    const float* W2   = (const float*)d_in[4];
    const float* b2   = (const float*)d_in[5];
    const float* Wout = (const float*)d_in[6];
    const float* bout = (const float*)d_in[7];
    float* out = (float*)d_out;

    const int N = in_sizes[0] / 128;
    const int E = in_sizes[1] / 2;
    const int* esrc = ei;
    const int* edst = ei + E;

    char* p = (char*)d_ws;
    auto alloc = [&](size_t bytes) {
        char* r = p;
        p += (bytes + 255) & ~(size_t)255;
        return (void*)r;
    };
    int*   cnt  = (int*)  alloc((size_t)N * 4);
    float* isd  = (float*)alloc((size_t)N * 4);
    int*   ell  = (int*)  alloc((size_t)N * CAPD * 4);
    uint*  Tb   = (uint*) alloc((size_t)N * 64 * 4);   // N x 128 bf16
    float* H    = (float*)alloc((size_t)N * 128 * 4);  // f32
    uint*  Wh1  = (uint*) alloc(8192 * 4);
    uint*  Wl1  = (uint*) alloc(8192 * 4);
    uint*  Wh2  = (uint*) alloc(8192 * 4);
    uint*  Wl2  = (uint*) alloc(8192 * 4);

    // Partition scratch aliases Tb (not live until gemm).
    const int nb  = (N + BSZ - 1) / BSZ;
    const int NB2 = (E + CHUNK - 1) / CHUNK;
    char* q = (char*)Tb;
    auto alloc2 = [&](size_t bytes) {
        char* r = q;
        q += (bytes + 255) & ~(size_t)255;
        return (void*)r;
    };
    unsigned* gSorted    = (unsigned*)alloc2((size_t)E * 4);
    int*      gHist      = (int*)     alloc2((size_t)nb * NB2 * 4);
    int*      gStart     = (int*)     alloc2((size_t)nb * NB2 * 4);
    int*      bucketBase = (int*)     alloc2((size_t)(nb + 1) * 4);

    p1_count  <<<NB2, 256, 0, stream>>>(edst, E, nb, gHist);
    p2_scan   <<<1,   256, 0, stream>>>(gHist, gStart, nb, NB2, bucketBase);
    p3_scatter<<<NB2, 256, 0, stream>>>(esrc, edst, E, nb, gStart, gSorted);
    p4_build  <<<nb,  256, 0, stream>>>(gSorted, bucketBase, N, cnt, isd, ell);

    wtb_kernel<<<2, 256, 0, stream>>>(W1, W2, Wh1, Wl1, Wh2, Wl2);

    const int gblocks = (N + 127) / 128;
    // Layer 1: Tb = bf16(diag(isd)*(x@W1)) ; H = relu(isd*(Tb_self + sum Tb_src) + b1)
    gemm_mfma<<<gblocks, 256, 0, stream>>>(x, Wh1, Wl1, isd, Tb, N);
    agg_kernel<<<(N + 3) / 4, 256, 0, stream>>>(Tb, ell, cnt, isd, b1, H, N);
    // Layer 2 (agg reads only Tb -> overwriting H is safe)
    gemm_mfma<<<gblocks, 256, 0, stream>>>(H, Wh2, Wl2, isd, Tb, N);
    agg_kernel<<<(N + 3) / 4, 256, 0, stream>>>(Tb, ell, cnt, isd, b2, H, N);
    // Head
    out_kernel<<<(N + 3) / 4, 256, 0, stream>>>(H, Wout, bout, out, N);
}

// Round 9
// 292.211 us; speedup vs baseline: 1.7549x; 1.2748x over previous
//
#include <hip/hip_runtime.h>
#include <cstddef>

#define CAPD 64
#define BSZ 512      // nodes per bucket
#define BSH 9        // log2(BSZ)
#define CHUNK 8192   // edges per partition block

typedef unsigned int uint;
typedef unsigned short ushort;
typedef float f32x4 __attribute__((ext_vector_type(4)));
typedef short bf16x8 __attribute__((ext_vector_type(8)));  // 8 bf16 = 4 VGPRs

// bf16 helpers: word = dimEven | dimOdd<<16
__device__ inline float bf_lo(uint v) { union { uint u; float f; } c; c.u = v << 16; return c.f; }
__device__ inline float bf_hi(uint v) { union { uint u; float f; } c; c.u = v & 0xFFFF0000u; return c.f; }
__device__ inline ushort bf_r(float x) {   // f32 -> bf16 RNE
    union { float f; uint u; } c; c.f = x;
    return (ushort)((c.u + 0x7FFFu + ((c.u >> 16) & 1u)) >> 16);
}
__device__ inline float bf_f(ushort h) {   // bf16 -> f32
    union { uint u; float f; } c; c.u = (uint)h << 16; return c.f;
}

// ---------- fill pipeline: counting-sort partition by dst bucket ----------

__global__ __launch_bounds__(256) void p1_count(const int* __restrict__ edst, int E,
                                                int nb, int* __restrict__ gHist) {
    __shared__ int hist[256];
    int bid = blockIdx.x, tid = threadIdx.x;
    hist[tid] = 0;
    __syncthreads();
    int e0 = bid * CHUNK, e1 = min(E, e0 + CHUNK);
    for (int e = e0 + tid; e < e1; e += 256)
        atomicAdd(&hist[edst[e] >> BSH], 1);
    __syncthreads();
    for (int i = tid; i < nb; i += 256)
        gHist[bid * nb + i] = hist[i];
}

// p2a: one block per bucket b. Scan that bucket's per-chunk counts (NB2 <= 256).
// gStart[j][b] = exclusive prefix within bucket; bucketTot[b] = total.
__global__ __launch_bounds__(256) void p2a_scan(const int* __restrict__ gHist,
                                                int* __restrict__ gStart,
                                                int nb, int NB2,
                                                int* __restrict__ bucketTot) {
    __shared__ int sc[256];
    int b = blockIdx.x, t = threadIdx.x;
    int v = (t < NB2) ? gHist[t * nb + b] : 0;
    sc[t] = v;
    __syncthreads();
    for (int off = 1; off < 256; off <<= 1) {
        int u = (t >= off) ? sc[t - off] : 0;
        __syncthreads();
        sc[t] += u;
        __syncthreads();
    }
    if (t < NB2) gStart[t * nb + b] = sc[t] - v;
    if (t == 255) bucketTot[b] = sc[255];
}

// p2b: single block. Exclusive scan of bucket totals -> bucketBase[0..nb].
__global__ __launch_bounds__(256) void p2b_scan(const int* __restrict__ bucketTot,
                                                int nb, int* __restrict__ bucketBase) {
    __shared__ int sc[256];
    int t = threadIdx.x;
    int v = (t < nb) ? bucketTot[t] : 0;
    sc[t] = v;
    __syncthreads();
    for (int off = 1; off < 256; off <<= 1) {
        int u = (t >= off) ? sc[t - off] : 0;
        __syncthreads();
        sc[t] += u;
        __syncthreads();
    }
    if (t < nb) bucketBase[t] = sc[t] - v;
    if (t == nb - 1) bucketBase[nb] = sc[t];
}

__global__ __launch_bounds__(256) void p3_scatter(const int* __restrict__ esrc,
                                                  const int* __restrict__ edst, int E,
                                                  int nb,
                                                  const int* __restrict__ gStart,
                                                  const int* __restrict__ bucketBase,
                                                  unsigned* __restrict__ gSorted) {
    __shared__ unsigned lds[CHUNK];
    __shared__ int hist[256], segoff[256], cursor[256], gbase[256], sc[256];
    int bid = blockIdx.x, tid = threadIdx.x;
    int e0 = bid * CHUNK, e1 = min(E, e0 + CHUNK);
    hist[tid] = 0;
    __syncthreads();
    for (int e = e0 + tid; e < e1; e += 256)
        atomicAdd(&hist[edst[e] >> BSH], 1);
    __syncthreads();
    sc[tid] = hist[tid];
    __syncthreads();
    for (int off = 1; off < 256; off <<= 1) {
        int v = (tid >= off) ? sc[tid - off] : 0;
        __syncthreads();
        sc[tid] += v;
        __syncthreads();
    }
    segoff[tid] = sc[tid] - hist[tid];
    cursor[tid] = segoff[tid];
    if (tid < nb) gbase[tid] = gStart[bid * nb + tid] + bucketBase[tid];
    __syncthreads();
    for (int e = e0 + tid; e < e1; e += 256) {
        int d = edst[e];
        int b = d >> BSH;
        int p = atomicAdd(&cursor[b], 1);
        lds[p] = (unsigned)esrc[e] | ((unsigned)(d & (BSZ - 1)) << 23);
    }
    __syncthreads();
    int wave = tid >> 6, lane = tid & 63;
    for (int b = wave; b < nb; b += 4) {
        int off = segoff[b], len = hist[b], gb = gbase[b];
        for (int i = lane; i < len; i += 64)
            gSorted[gb + i] = lds[off + i];
    }
}

__global__ __launch_bounds__(256) void p4_build(const unsigned* __restrict__ gSorted,
                                                const int* __restrict__ bucketBase,
                                                int N, int* __restrict__ cnt,
                                                float* __restrict__ isd,
                                                int* __restrict__ ell) {
    __shared__ unsigned ellL[BSZ * CAPD];  // 128KB
    __shared__ int cntL[BSZ];
    int b = blockIdx.x, tid = threadIdx.x;
    int n0 = b * BSZ;
    for (int i = tid; i < BSZ; i += 256) cntL[i] = 0;
    __syncthreads();
    int base = bucketBase[b], len = bucketBase[b + 1] - base;
    for (int i = tid; i < len; i += 256) {
        unsigned e = gSorted[base + i];
        int dl = (int)(e >> 23);
        int src = (int)(e & 0x7FFFFFu);
        int p = atomicAdd(&cntL[dl], 1);
        if (p < CAPD) ellL[dl * CAPD + p] = (unsigned)src;
    }
    __syncthreads();
    int nValid = min(BSZ, N - n0);
    int total = nValid * CAPD;
    const int* ellLi = (const int*)ellL;
    for (int i = tid; i < total; i += 256)
        ell[(size_t)n0 * CAPD + i] = ellLi[i];
    for (int i = tid; i < nValid; i += 256) {
        int c = cntL[i];
        cnt[n0 + i] = c;
        isd[n0 + i] = rsqrtf(1.0f + (float)c);
    }
}

// ---------- W prep: W[128][128] f32 -> transposed split-bf16 hi/lo ----------
__global__ __launch_bounds__(256) void wtb_kernel(const float* __restrict__ Wa,
                                                  const float* __restrict__ Wb,
                                                  uint* __restrict__ OaHi, uint* __restrict__ OaLo,
                                                  uint* __restrict__ ObHi, uint* __restrict__ ObLo) {
    const float* W = blockIdx.x ? Wb : Wa;
    uint* OHi = blockIdx.x ? ObHi : OaHi;
    uint* OLo = blockIdx.x ? ObLo : OaLo;
    __shared__ float ws[128][129];
    int tid = threadIdx.x;
#pragma unroll
    for (int j = 0; j < 16; ++j) {
        int q = tid + 256 * j;          // 4096 float4 chunks
        int k = q >> 5, c = (q & 31) * 4;
        float4 v = *reinterpret_cast<const float4*>(W + k * 128 + c);
        ws[k][c] = v.x; ws[k][c + 1] = v.y; ws[k][c + 2] = v.z; ws[k][c + 3] = v.w;
    }
    __syncthreads();
#pragma unroll
    for (int j = 0; j < 32; ++j) {
        int q = tid + 256 * j;          // 8192 words
        int ncol = q >> 6, kw = q & 63;
        float w0 = ws[2 * kw][ncol], w1 = ws[2 * kw + 1][ncol];
        ushort h0 = bf_r(w0), h1 = bf_r(w1);
        ushort l0 = bf_r(w0 - bf_f(h0)), l1 = bf_r(w1 - bf_f(h1));
        OHi[q] = (uint)h0 | ((uint)h1 << 16);
        OLo[q] = (uint)l0 | ((uint)l1 << 16);
    }
}

// ---------- MFMA GEMM (bf16x3 split = f32-accurate): Tb = bf16(diag(scale)*(A @ W)) ----------
__global__ __launch_bounds__(256) void gemm_mfma(const float* __restrict__ A,
                                                 const uint* __restrict__ Whi,
                                                 const uint* __restrict__ Wlo,
                                                 const float* __restrict__ scale,
                                                 uint* __restrict__ Tb, int n) {
    __shared__ uint SH[32768];  // 128KB
    char* shb = (char*)SH;
    const int tid = threadIdx.x;
    const int m0 = blockIdx.x * 128;

    // Stage A: 128 rows x 128 f32 = 4096 x 16B chunks; split into hi/lo bf16.
#pragma unroll
    for (int j = 0; j < 16; ++j) {
        int q = tid + 256 * j;
        int row = q >> 5, c = q & 31;
        int grow = m0 + row;
        float4 v = make_float4(0.f, 0.f, 0.f, 0.f);
        if (grow < n) v = *reinterpret_cast<const float4*>(A + (size_t)grow * 128 + c * 4);
        ushort h0 = bf_r(v.x), h1 = bf_r(v.y), h2 = bf_r(v.z), h3 = bf_r(v.w);
        uint2 hi = make_uint2((uint)h0 | ((uint)h1 << 16), (uint)h2 | ((uint)h3 << 16));
        uint2 lo = make_uint2(
            (uint)bf_r(v.x - bf_f(h0)) | ((uint)bf_r(v.y - bf_f(h1)) << 16),
            (uint)bf_r(v.z - bf_f(h2)) | ((uint)bf_r(v.w - bf_f(h3)) << 16));
        int off = (c * 8) ^ ((row & 7) << 4);
        *reinterpret_cast<uint2*>(shb + row * 256 + off) = hi;
        *reinterpret_cast<uint2*>(shb + 32768 + row * 256 + off) = lo;
    }
#pragma unroll
    for (int j = 0; j < 8; ++j) {
        int q = tid + 256 * j;
        int col = q >> 4, c16 = q & 15;
        int off = (c16 * 16) ^ ((col & 7) << 4);
        uint4 vh = *reinterpret_cast<const uint4*>(Whi + col * 64 + c16 * 4);
        uint4 vl = *reinterpret_cast<const uint4*>(Wlo + col * 64 + c16 * 4);
        *reinterpret_cast<uint4*>(shb + 65536 + col * 256 + off) = vh;
        *reinterpret_cast<uint4*>(shb + 98304 + col * 256 + off) = vl;
    }
    __syncthreads();

    const int w = tid >> 6, l = tid & 63;
    const int lrow = l & 15, kg = l >> 4;
    const int swz = (lrow & 7) << 4;

    f32x4 acc[2][8] = {};
#pragma unroll
    for (int kk = 0; kk < 4; ++kk) {
        const int koff = (kk * 64 + kg * 16) ^ swz;
        bf16x8 ah[2], al[2], bh[8], bl[8];
#pragma unroll
        for (int mr = 0; mr < 2; ++mr) {
            int r = w * 32 + mr * 16 + lrow;
            ah[mr] = *reinterpret_cast<const bf16x8*>(shb + r * 256 + koff);
            al[mr] = *reinterpret_cast<const bf16x8*>(shb + 32768 + r * 256 + koff);
        }
#pragma unroll
        for (int nc = 0; nc < 8; ++nc) {
            int c = nc * 16 + lrow;
            bh[nc] = *reinterpret_cast<const bf16x8*>(shb + 65536 + c * 256 + koff);
            bl[nc] = *reinterpret_cast<const bf16x8*>(shb + 98304 + c * 256 + koff);
        }
#pragma unroll
        for (int mr = 0; mr < 2; ++mr)
#pragma unroll
            for (int nc = 0; nc < 8; ++nc) {
                acc[mr][nc] = __builtin_amdgcn_mfma_f32_16x16x32_bf16(ah[mr], bh[nc], acc[mr][nc], 0, 0, 0);
                acc[mr][nc] = __builtin_amdgcn_mfma_f32_16x16x32_bf16(ah[mr], bl[nc], acc[mr][nc], 0, 0, 0);
                acc[mr][nc] = __builtin_amdgcn_mfma_f32_16x16x32_bf16(al[mr], bh[nc], acc[mr][nc], 0, 0, 0);
            }
    }
    __syncthreads();

    // C/D layout (m89): col = lane&15, row = (lane>>4)*4 + reg. Scale + pack via LDS.
    ushort* Cs = (ushort*)SH;   // [128][136] bf16
#pragma unroll
    for (int mr = 0; mr < 2; ++mr) {
        int rb = w * 32 + mr * 16 + kg * 4;
#pragma unroll
        for (int i = 0; i < 4; ++i) {
            int grow = m0 + rb + i;
            float s = (grow < n) ? scale[grow] : 0.f;
#pragma unroll
            for (int nc = 0; nc < 8; ++nc)
                Cs[(rb + i) * 136 + nc * 16 + lrow] = bf_r(s * acc[mr][nc][i]);
        }
    }
    __syncthreads();
    const uint* Cw = (const uint*)SH;
#pragma unroll
    for (int j = 0; j < 8; ++j) {
        int q = tid + 256 * j;
        int row = q >> 4, c4 = q & 15;
        int grow = m0 + row;
        if (grow < n) {
            uint4 v = *reinterpret_cast<const uint4*>(Cw + row * 68 + c4 * 4);
            *reinterpret_cast<uint4*>(Tb + (size_t)grow * 64 + c4 * 4) = v;
        }
    }
}

// ---------- aggregation (bf16 gather in, f32 out) ----------
__global__ __launch_bounds__(256) void agg_kernel(const uint* __restrict__ Tb,
                                                  const int* __restrict__ ell,
                                                  const int* __restrict__ cnt,
                                                  const float* __restrict__ isd,
                                                  const float* __restrict__ bias,
                                                  float* __restrict__ H, int n) {
    int gw = (int)((blockIdx.x * 256 + threadIdx.x) >> 6);
    int lane = threadIdx.x & 63;
    if (gw >= n) return;
    float di = isd[gw];
    int c = cnt[gw];
    if (c > CAPD) c = CAPD;
    const int* row = ell + (size_t)gw * CAPD;
    uint sv = Tb[(size_t)gw * 64 + lane];
    float acc0 = bf_lo(sv), acc1 = bf_hi(sv);
    int j = 0;
    for (; j + 8 <= c; j += 8) {
        int4 sa = *reinterpret_cast<const int4*>(row + j);
        int4 sb = *reinterpret_cast<const int4*>(row + j + 4);
        uint v0 = Tb[(size_t)sa.x * 64 + lane];
        uint v1 = Tb[(size_t)sa.y * 64 + lane];
        uint v2 = Tb[(size_t)sa.z * 64 + lane];
        uint v3 = Tb[(size_t)sa.w * 64 + lane];
        uint v4 = Tb[(size_t)sb.x * 64 + lane];
        uint v5 = Tb[(size_t)sb.y * 64 + lane];
        uint v6 = Tb[(size_t)sb.z * 64 + lane];
        uint v7 = Tb[(size_t)sb.w * 64 + lane];
        acc0 += ((bf_lo(v0) + bf_lo(v1)) + (bf_lo(v2) + bf_lo(v3))) +
                ((bf_lo(v4) + bf_lo(v5)) + (bf_lo(v6) + bf_lo(v7)));
        acc1 += ((bf_hi(v0) + bf_hi(v1)) + (bf_hi(v2) + bf_hi(v3))) +
                ((bf_hi(v4) + bf_hi(v5)) + (bf_hi(v6) + bf_hi(v7)));
    }
    for (; j + 4 <= c; j += 4) {
        int4 s4 = *reinterpret_cast<const int4*>(row + j);
        uint v0 = Tb[(size_t)s4.x * 64 + lane];
        uint v1 = Tb[(size_t)s4.y * 64 + lane];
        uint v2 = Tb[(size_t)s4.z * 64 + lane];
        uint v3 = Tb[(size_t)s4.w * 64 + lane];
        acc0 += (bf_lo(v0) + bf_lo(v1)) + (bf_lo(v2) + bf_lo(v3));
        acc1 += (bf_hi(v0) + bf_hi(v1)) + (bf_hi(v2) + bf_hi(v3));
    }
    for (; j < c; ++j) {
        uint v = Tb[(size_t)row[j] * 64 + lane];
        acc0 += bf_lo(v);
        acc1 += bf_hi(v);
    }
    float2 bv = *reinterpret_cast<const float2*>(bias + lane * 2);
    float h0 = fmaxf(fmaf(di, acc0, bv.x), 0.f);
    float h1 = fmaxf(fmaf(di, acc1, bv.y), 0.f);
    *reinterpret_cast<float2*>(H + (size_t)gw * 128 + lane * 2) = make_float2(h0, h1);
}

// ---------- layer-2 agg fused with output head ----------
// out[i] = sigmoid( dot(relu(isd*(Tb_self+sum Tb_src)+b2), Wout) + bout )
__global__ __launch_bounds__(256) void agg_out_kernel(const uint* __restrict__ Tb,
                                                      const int* __restrict__ ell,
                                                      const int* __restrict__ cnt,
                                                      const float* __restrict__ isd,
                                                      const float* __restrict__ bias,
                                                      const float* __restrict__ Wout,
                                                      const float* __restrict__ bout,
                                                      float* __restrict__ out, int n) {
    int gw = (int)((blockIdx.x * 256 + threadIdx.x) >> 6);
    int lane = threadIdx.x & 63;
    if (gw >= n) return;
    float di = isd[gw];
    int c = cnt[gw];
    if (c > CAPD) c = CAPD;
    const int* row = ell + (size_t)gw * CAPD;
    uint sv = Tb[(size_t)gw * 64 + lane];
    float acc0 = bf_lo(sv), acc1 = bf_hi(sv);
    int j = 0;
    for (; j + 8 <= c; j += 8) {
        int4 sa = *reinterpret_cast<const int4*>(row + j);
        int4 sb = *reinterpret_cast<const int4*>(row + j + 4);
        uint v0 = Tb[(size_t)sa.x * 64 + lane];
        uint v1 = Tb[(size_t)sa.y * 64 + lane];
        uint v2 = Tb[(size_t)sa.z * 64 + lane];
        uint v3 = Tb[(size_t)sa.w * 64 + lane];
        uint v4 = Tb[(size_t)sb.x * 64 + lane];
        uint v5 = Tb[(size_t)sb.y * 64 + lane];
        uint v6 = Tb[(size_t)sb.z * 64 + lane];
        uint v7 = Tb[(size_t)sb.w * 64 + lane];
        acc0 += ((bf_lo(v0) + bf_lo(v1)) + (bf_lo(v2) + bf_lo(v3))) +
                ((bf_lo(v4) + bf_lo(v5)) + (bf_lo(v6) + bf_lo(v7)));
        acc1 += ((bf_hi(v0) + bf_hi(v1)) + (bf_hi(v2) + bf_hi(v3))) +
                ((bf_hi(v4) + bf_hi(v5)) + (bf_hi(v6) + bf_hi(v7)));
    }
    for (; j + 4 <= c; j += 4) {
        int4 s4 = *reinterpret_cast<const int4*>(row + j);
        uint v0 = Tb[(size_t)s4.x * 64 + lane];
        uint v1 = Tb[(size_t)s4.y * 64 + lane];
        uint v2 = Tb[(size_t)s4.z * 64 + lane];
        uint v3 = Tb[(size_t)s4.w * 64 + lane];
        acc0 += (bf_lo(v0) + bf_lo(v1)) + (bf_lo(v2) + bf_lo(v3));
        acc1 += (bf_hi(v0) + bf_hi(v1)) + (bf_hi(v2) + bf_hi(v3));
    }
    for (; j < c; ++j) {
        uint v = Tb[(size_t)row[j] * 64 + lane];
        acc0 += bf_lo(v);
        acc1 += bf_hi(v);
    }
    float2 bv = *reinterpret_cast<const float2*>(bias + lane * 2);
    float h0 = fmaxf(fmaf(di, acc0, bv.x), 0.f);
    float h1 = fmaxf(fmaf(di, acc1, bv.y), 0.f);
    float2 wv = *reinterpret_cast<const float2*>(Wout + lane * 2);
    float v = fmaf(h0, wv.x, h1 * wv.y);
#pragma unroll
    for (int off = 32; off > 0; off >>= 1) v += __shfl_xor(v, off, 64);
    if (lane == 0) out[gw] = 1.f / (1.f + expf(-(v + bout[0])));
}

extern "C" void kernel_launch(void* const* d_in, const int* in_sizes, int n_in,
                              void* d_out, int out_size, void* d_ws, size_t ws_size,
                              hipStream_t stream) {
    const float* x    = (const float*)d_in[0];
    const int*   ei   = (const int*)d_in[1];
    const float* W1   = (const float*)d_in[2];
    const float* b1   = (const float*)d_in[3];
    const float* W2   = (const float*)d_in[4];
    const float* b2   = (const float*)d_in[5];
    const float* Wout = (const float*)d_in[6];
    const float* bout = (const float*)d_in[7];
    float* out = (float*)d_out;

    const int N = in_sizes[0] / 128;
    const int E = in_sizes[1] / 2;
    const int* esrc = ei;
    const int* edst = ei + E;

    char* p = (char*)d_ws;
    auto alloc = [&](size_t bytes) {
        char* r = p;
        p += (bytes + 255) & ~(size_t)255;
        return (void*)r;
    };
    int*   cnt  = (int*)  alloc((size_t)N * 4);
    float* isd  = (float*)alloc((size_t)N * 4);
    int*   ell  = (int*)  alloc((size_t)N * CAPD * 4);
    uint*  Tb   = (uint*) alloc((size_t)N * 64 * 4);   // N x 128 bf16
    float* H    = (float*)alloc((size_t)N * 128 * 4);  // f32 (layer-1 only)
    uint*  Wh1  = (uint*) alloc(8192 * 4);
    uint*  Wl1  = (uint*) alloc(8192 * 4);
    uint*  Wh2  = (uint*) alloc(8192 * 4);
    uint*  Wl2  = (uint*) alloc(8192 * 4);

    // Partition scratch aliases Tb+H (not live until gemm).
    const int nb  = (N + BSZ - 1) / BSZ;
    const int NB2 = (E + CHUNK - 1) / CHUNK;
    char* q = (char*)Tb;
    auto alloc2 = [&](size_t bytes) {
        char* r = q;
        q += (bytes + 255) & ~(size_t)255;
        return (void*)r;
    };
    unsigned* gSorted    = (unsigned*)alloc2((size_t)E * 4);
    int*      gHist      = (int*)     alloc2((size_t)nb * NB2 * 4);
    int*      gStart     = (int*)     alloc2((size_t)nb * NB2 * 4);
    int*      bucketTot  = (int*)     alloc2((size_t)nb * 4);
    int*      bucketBase = (int*)     alloc2((size_t)(nb + 1) * 4);

    p1_count  <<<NB2, 256, 0, stream>>>(edst, E, nb, gHist);
    p2a_scan  <<<nb,  256, 0, stream>>>(gHist, gStart, nb, NB2, bucketTot);
    p2b_scan  <<<1,   256, 0, stream>>>(bucketTot, nb, bucketBase);
    p3_scatter<<<NB2, 256, 0, stream>>>(esrc, edst, E, nb, gStart, bucketBase, gSorted);
    p4_build  <<<nb,  256, 0, stream>>>(gSorted, bucketBase, N, cnt, isd, ell);

    wtb_kernel<<<2, 256, 0, stream>>>(W1, W2, Wh1, Wl1, Wh2, Wl2);

    const int gblocks = (N + 127) / 128;
    // Layer 1: Tb = bf16(diag(isd)*(x@W1)) ; H = relu(isd*(Tb_self + sum Tb_src) + b1)
    gemm_mfma<<<gblocks, 256, 0, stream>>>(x, Wh1, Wl1, isd, Tb, N);
    agg_kernel<<<(N + 3) / 4, 256, 0, stream>>>(Tb, ell, cnt, isd, b1, H, N);
    // Layer 2 + fused head (agg reads only Tb; out written directly)
    gemm_mfma<<<gblocks, 256, 0, stream>>>(H, Wh2, Wl2, isd, Tb, N);
    agg_out_kernel<<<(N + 3) / 4, 256, 0, stream>>>(Tb, ell, cnt, isd, b2, Wout, bout, out, N);
}

// Round 10
// 233.525 us; speedup vs baseline: 2.1959x; 1.2513x over previous
//
#include <hip/hip_runtime.h>
#include <cstddef>

#define CAPD 64
#define BSZ 512      // nodes per bucket
#define BSH 9        // log2(BSZ)
#define CHUNK 8192   // edges per partition block

typedef unsigned int uint;
typedef unsigned short ushort;
typedef float f32x4 __attribute__((ext_vector_type(4)));
typedef _Float16 f16x8 __attribute__((ext_vector_type(8)));  // 8 fp16 = 4 VGPRs

// fp16 helpers: word = dimEven | dimOdd<<16
__device__ inline float h_lo(uint v) {
    union { ushort u; _Float16 h; } c; c.u = (ushort)(v & 0xFFFFu); return (float)c.h;
}
__device__ inline float h_hi(uint v) {
    union { ushort u; _Float16 h; } c; c.u = (ushort)(v >> 16); return (float)c.h;
}
__device__ inline ushort h_bits(float x) {
    union { _Float16 h; ushort u; } c; c.h = (_Float16)x; return c.u;
}
__device__ inline uint h_pack(float a, float b) {
    return (uint)h_bits(a) | ((uint)h_bits(b) << 16);
}

// ---------- fill pipeline: counting-sort partition by dst bucket ----------

__global__ __launch_bounds__(256) void p1_count(const int* __restrict__ edst, int E,
                                                int nb, int* __restrict__ gHist) {
    __shared__ int hist[256];
    int bid = blockIdx.x, tid = threadIdx.x;
    hist[tid] = 0;
    __syncthreads();
    int e0 = bid * CHUNK, e1 = min(E, e0 + CHUNK);
    for (int e = e0 + tid; e < e1; e += 256)
        atomicAdd(&hist[edst[e] >> BSH], 1);
    __syncthreads();
    for (int i = tid; i < nb; i += 256)
        gHist[bid * nb + i] = hist[i];
}

// p2a: one block per bucket b. Scan that bucket's per-chunk counts (NB2 <= 256).
__global__ __launch_bounds__(256) void p2a_scan(const int* __restrict__ gHist,
                                                int* __restrict__ gStart,
                                                int nb, int NB2,
                                                int* __restrict__ bucketTot) {
    __shared__ int sc[256];
    int b = blockIdx.x, t = threadIdx.x;
    int v = (t < NB2) ? gHist[t * nb + b] : 0;
    sc[t] = v;
    __syncthreads();
    for (int off = 1; off < 256; off <<= 1) {
        int u = (t >= off) ? sc[t - off] : 0;
        __syncthreads();
        sc[t] += u;
        __syncthreads();
    }
    if (t < NB2) gStart[t * nb + b] = sc[t] - v;
    if (t == 255) bucketTot[b] = sc[255];
}

// p2b: single block. Exclusive scan of bucket totals -> bucketBase[0..nb].
__global__ __launch_bounds__(256) void p2b_scan(const int* __restrict__ bucketTot,
                                                int nb, int* __restrict__ bucketBase) {
    __shared__ int sc[256];
    int t = threadIdx.x;
    int v = (t < nb) ? bucketTot[t] : 0;
    sc[t] = v;
    __syncthreads();
    for (int off = 1; off < 256; off <<= 1) {
        int u = (t >= off) ? sc[t - off] : 0;
        __syncthreads();
        sc[t] += u;
        __syncthreads();
    }
    if (t < nb) bucketBase[t] = sc[t] - v;
    if (t == nb - 1) bucketBase[nb] = sc[t];
}

__global__ __launch_bounds__(256) void p3_scatter(const int* __restrict__ esrc,
                                                  const int* __restrict__ edst, int E,
                                                  int nb,
                                                  const int* __restrict__ gStart,
                                                  const int* __restrict__ bucketBase,
                                                  unsigned* __restrict__ gSorted) {
    __shared__ unsigned lds[CHUNK];
    __shared__ int hist[256], segoff[256], cursor[256], gbase[256], sc[256];
    int bid = blockIdx.x, tid = threadIdx.x;
    int e0 = bid * CHUNK, e1 = min(E, e0 + CHUNK);
    hist[tid] = 0;
    __syncthreads();
    for (int e = e0 + tid; e < e1; e += 256)
        atomicAdd(&hist[edst[e] >> BSH], 1);
    __syncthreads();
    sc[tid] = hist[tid];
    __syncthreads();
    for (int off = 1; off < 256; off <<= 1) {
        int v = (tid >= off) ? sc[tid - off] : 0;
        __syncthreads();
        sc[tid] += v;
        __syncthreads();
    }
    segoff[tid] = sc[tid] - hist[tid];
    cursor[tid] = segoff[tid];
    if (tid < nb) gbase[tid] = gStart[bid * nb + tid] + bucketBase[tid];
    __syncthreads();
    for (int e = e0 + tid; e < e1; e += 256) {
        int d = edst[e];
        int b = d >> BSH;
        int p = atomicAdd(&cursor[b], 1);
        lds[p] = (unsigned)esrc[e] | ((unsigned)(d & (BSZ - 1)) << 23);
    }
    __syncthreads();
    int wave = tid >> 6, lane = tid & 63;
    for (int b = wave; b < nb; b += 4) {
        int off = segoff[b], len = hist[b], gb = gbase[b];
        for (int i = lane; i < len; i += 64)
            gSorted[gb + i] = lds[off + i];
    }
}

__global__ __launch_bounds__(256) void p4_build(const unsigned* __restrict__ gSorted,
                                                const int* __restrict__ bucketBase,
                                                int N, int* __restrict__ cnt,
                                                float* __restrict__ isd,
                                                int* __restrict__ ell) {
    __shared__ unsigned ellL[BSZ * CAPD];  // 128KB
    __shared__ int cntL[BSZ];
    int b = blockIdx.x, tid = threadIdx.x;
    int n0 = b * BSZ;
    for (int i = tid; i < BSZ; i += 256) cntL[i] = 0;
    __syncthreads();
    int base = bucketBase[b], len = bucketBase[b + 1] - base;
    for (int i = tid; i < len; i += 256) {
        unsigned e = gSorted[base + i];
        int dl = (int)(e >> 23);
        int src = (int)(e & 0x7FFFFFu);
        int p = atomicAdd(&cntL[dl], 1);
        if (p < CAPD) ellL[dl * CAPD + p] = (unsigned)src;
    }
    __syncthreads();
    int nValid = min(BSZ, N - n0);
    int total = nValid * CAPD;
    const int* ellLi = (const int*)ellL;
    for (int i = tid; i < total; i += 256)
        ell[(size_t)n0 * CAPD + i] = ellLi[i];
    for (int i = tid; i < nValid; i += 256) {
        int c = cntL[i];
        cnt[n0 + i] = c;
        isd[n0 + i] = rsqrtf(1.0f + (float)c);
    }
}

// ---------- W prep: W[128][128] f32 -> transposed fp16 [col][64 kwords] ----------
__global__ __launch_bounds__(256) void wtb_kernel(const float* __restrict__ Wa,
                                                  const float* __restrict__ Wb,
                                                  uint* __restrict__ Oa,
                                                  uint* __restrict__ Ob) {
    const float* W = blockIdx.x ? Wb : Wa;
    uint* O = blockIdx.x ? Ob : Oa;
    __shared__ float ws[128][129];
    int tid = threadIdx.x;
#pragma unroll
    for (int j = 0; j < 16; ++j) {
        int q = tid + 256 * j;          // 4096 float4 chunks
        int k = q >> 5, c = (q & 31) * 4;
        float4 v = *reinterpret_cast<const float4*>(W + k * 128 + c);
        ws[k][c] = v.x; ws[k][c + 1] = v.y; ws[k][c + 2] = v.z; ws[k][c + 3] = v.w;
    }
    __syncthreads();
#pragma unroll
    for (int j = 0; j < 32; ++j) {
        int q = tid + 256 * j;          // 8192 words
        int ncol = q >> 6, kw = q & 63;
        O[q] = h_pack(ws[2 * kw][ncol], ws[2 * kw + 1][ncol]);
    }
}

// ---------- fp16 MFMA GEMM: Tb = fp16( diag(scale) * (A @ W) ) ----------
// A: f32 [n][128] (aF16=0) or fp16-pair [n][64] (aF16=1). Wt: [128 cols][64 kwords] fp16.
// Block 128x128, 4 waves, LDS 64KB -> 2 blocks/CU.
// Swizzle: byte ^= ((row&7)<<4) kills the 256B-stride bank conflict (G4/T2).
__global__ __launch_bounds__(256) void gemm_mfma(const void* __restrict__ A, int aF16,
                                                 const uint* __restrict__ Wt,
                                                 const float* __restrict__ scale,
                                                 uint* __restrict__ Tb, int n) {
    __shared__ uint SH[16384];  // 64KB: A [0,32K), W [32K,64K); epilogue reuses
    char* shb = (char*)SH;
    const int tid = threadIdx.x;
    const int m0 = blockIdx.x * 128;

    // Stage A: 128 rows x 256B fp16 = 2048 x 16B chunks, 8 iters.
    if (aF16) {
        const uint* Af = (const uint*)A;
#pragma unroll
        for (int j = 0; j < 8; ++j) {
            int q = tid + 256 * j;
            int row = q >> 4, c16 = q & 15;
            int grow = m0 + row;
            uint4 v = make_uint4(0u, 0u, 0u, 0u);
            if (grow < n) v = *reinterpret_cast<const uint4*>(Af + (size_t)grow * 64 + c16 * 4);
            *reinterpret_cast<uint4*>(shb + row * 256 + ((c16 * 16) ^ ((row & 7) << 4))) = v;
        }
    } else {
        const float* Af = (const float*)A;
#pragma unroll
        for (int j = 0; j < 8; ++j) {
            int q = tid + 256 * j;
            int row = q >> 4, c16 = q & 15;
            int grow = m0 + row;
            uint4 o = make_uint4(0u, 0u, 0u, 0u);
            if (grow < n) {
                float4 v0 = *reinterpret_cast<const float4*>(Af + (size_t)grow * 128 + c16 * 8);
                float4 v1 = *reinterpret_cast<const float4*>(Af + (size_t)grow * 128 + c16 * 8 + 4);
                o.x = h_pack(v0.x, v0.y); o.y = h_pack(v0.z, v0.w);
                o.z = h_pack(v1.x, v1.y); o.w = h_pack(v1.z, v1.w);
            }
            *reinterpret_cast<uint4*>(shb + row * 256 + ((c16 * 16) ^ ((row & 7) << 4))) = o;
        }
    }
    // Stage W: 128 cols x 256B = 2048 x 16B chunks, 8 iters.
#pragma unroll
    for (int j = 0; j < 8; ++j) {
        int q = tid + 256 * j;
        int col = q >> 4, c16 = q & 15;
        uint4 v = *reinterpret_cast<const uint4*>(Wt + col * 64 + c16 * 4);
        *reinterpret_cast<uint4*>(shb + 32768 + col * 256 + ((c16 * 16) ^ ((col & 7) << 4))) = v;
    }
    __syncthreads();

    const int w = tid >> 6, l = tid & 63;
    const int lrow = l & 15, kg = l >> 4;
    const int swz = (lrow & 7) << 4;

    f32x4 acc[2][8] = {};
#pragma unroll
    for (int kk = 0; kk < 4; ++kk) {
        const int koff = (kk * 64 + kg * 16) ^ swz;
        f16x8 a[2], b[8];
#pragma unroll
        for (int mr = 0; mr < 2; ++mr) {
            int r = w * 32 + mr * 16 + lrow;
            a[mr] = *reinterpret_cast<const f16x8*>(shb + r * 256 + koff);
        }
#pragma unroll
        for (int nc = 0; nc < 8; ++nc) {
            int c = nc * 16 + lrow;
            b[nc] = *reinterpret_cast<const f16x8*>(shb + 32768 + c * 256 + koff);
        }
#pragma unroll
        for (int mr = 0; mr < 2; ++mr)
#pragma unroll
            for (int nc = 0; nc < 8; ++nc)
                acc[mr][nc] = __builtin_amdgcn_mfma_f32_16x16x32_f16(a[mr], b[nc], acc[mr][nc], 0, 0, 0);
    }
    __syncthreads();  // tiles consumed; reuse LDS for epilogue transpose

    // C/D layout (m89): col = lane&15, row = (lane>>4)*4 + reg. Scale + pack via LDS.
    ushort* Cs = (ushort*)SH;   // [128][136] fp16 (pad breaks bank alignment)
#pragma unroll
    for (int mr = 0; mr < 2; ++mr) {
        int rb = w * 32 + mr * 16 + kg * 4;
#pragma unroll
        for (int i = 0; i < 4; ++i) {
            int grow = m0 + rb + i;
            float s = (grow < n) ? scale[grow] : 0.f;
#pragma unroll
            for (int nc = 0; nc < 8; ++nc)
                Cs[(rb + i) * 136 + nc * 16 + lrow] = h_bits(s * acc[mr][nc][i]);
        }
    }
    __syncthreads();
    const uint* Cw = (const uint*)SH;             // stride 68 words/row
#pragma unroll
    for (int j = 0; j < 8; ++j) {
        int q = tid + 256 * j;
        int row = q >> 4, c4 = q & 15;
        int grow = m0 + row;
        if (grow < n) {
            uint4 v = *reinterpret_cast<const uint4*>(Cw + row * 68 + c4 * 4);
            *reinterpret_cast<uint4*>(Tb + (size_t)grow * 64 + c4 * 4) = v;
        }
    }
}

// ---------- aggregation (fp16 gather in, fp16 out) ----------
// Hb[i] = fp16( relu( isd[i]*(Tb[i] + sum_j Tb[src_j]) + bias ) ), lane l holds dims 2l,2l+1.
__global__ __launch_bounds__(256) void agg_kernel(const uint* __restrict__ Tb,
                                                  const int* __restrict__ ell,
                                                  const int* __restrict__ cnt,
                                                  const float* __restrict__ isd,
                                                  const float* __restrict__ bias,
                                                  uint* __restrict__ Hb, int n) {
    int gw = (int)((blockIdx.x * 256 + threadIdx.x) >> 6);
    int lane = threadIdx.x & 63;
    if (gw >= n) return;
    float di = isd[gw];
    int c = cnt[gw];
    if (c > CAPD) c = CAPD;
    const int* row = ell + (size_t)gw * CAPD;
    uint sv = Tb[(size_t)gw * 64 + lane];
    float acc0 = h_lo(sv), acc1 = h_hi(sv);
    int j = 0;
    for (; j + 8 <= c; j += 8) {
        int4 sa = *reinterpret_cast<const int4*>(row + j);
        int4 sb = *reinterpret_cast<const int4*>(row + j + 4);
        uint v0 = Tb[(size_t)sa.x * 64 + lane];
        uint v1 = Tb[(size_t)sa.y * 64 + lane];
        uint v2 = Tb[(size_t)sa.z * 64 + lane];
        uint v3 = Tb[(size_t)sa.w * 64 + lane];
        uint v4 = Tb[(size_t)sb.x * 64 + lane];
        uint v5 = Tb[(size_t)sb.y * 64 + lane];
        uint v6 = Tb[(size_t)sb.z * 64 + lane];
        uint v7 = Tb[(size_t)sb.w * 64 + lane];
        acc0 += ((h_lo(v0) + h_lo(v1)) + (h_lo(v2) + h_lo(v3))) +
                ((h_lo(v4) + h_lo(v5)) + (h_lo(v6) + h_lo(v7)));
        acc1 += ((h_hi(v0) + h_hi(v1)) + (h_hi(v2) + h_hi(v3))) +
                ((h_hi(v4) + h_hi(v5)) + (h_hi(v6) + h_hi(v7)));
    }
    for (; j + 4 <= c; j += 4) {
        int4 s4 = *reinterpret_cast<const int4*>(row + j);
        uint v0 = Tb[(size_t)s4.x * 64 + lane];
        uint v1 = Tb[(size_t)s4.y * 64 + lane];
        uint v2 = Tb[(size_t)s4.z * 64 + lane];
        uint v3 = Tb[(size_t)s4.w * 64 + lane];
        acc0 += (h_lo(v0) + h_lo(v1)) + (h_lo(v2) + h_lo(v3));
        acc1 += (h_hi(v0) + h_hi(v1)) + (h_hi(v2) + h_hi(v3));
    }
    for (; j < c; ++j) {
        uint v = Tb[(size_t)row[j] * 64 + lane];
        acc0 += h_lo(v);
        acc1 += h_hi(v);
    }
    float2 bv = *reinterpret_cast<const float2*>(bias + lane * 2);
    float h0 = fmaxf(fmaf(di, acc0, bv.x), 0.f);
    float h1 = fmaxf(fmaf(di, acc1, bv.y), 0.f);
    Hb[(size_t)gw * 64 + lane] = h_pack(h0, h1);
}

// ---------- layer-2 agg fused with output head ----------
__global__ __launch_bounds__(256) void agg_out_kernel(const uint* __restrict__ Tb,
                                                      const int* __restrict__ ell,
                                                      const int* __restrict__ cnt,
                                                      const float* __restrict__ isd,
                                                      const float* __restrict__ bias,
                                                      const float* __restrict__ Wout,
                                                      const float* __restrict__ bout,
                                                      float* __restrict__ out, int n) {
    int gw = (int)((blockIdx.x * 256 + threadIdx.x) >> 6);
    int lane = threadIdx.x & 63;
    if (gw >= n) return;
    float di = isd[gw];
    int c = cnt[gw];
    if (c > CAPD) c = CAPD;
    const int* row = ell + (size_t)gw * CAPD;
    uint sv = Tb[(size_t)gw * 64 + lane];
    float acc0 = h_lo(sv), acc1 = h_hi(sv);
    int j = 0;
    for (; j + 8 <= c; j += 8) {
        int4 sa = *reinterpret_cast<const int4*>(row + j);
        int4 sb = *reinterpret_cast<const int4*>(row + j + 4);
        uint v0 = Tb[(size_t)sa.x * 64 + lane];
        uint v1 = Tb[(size_t)sa.y * 64 + lane];
        uint v2 = Tb[(size_t)sa.z * 64 + lane];
        uint v3 = Tb[(size_t)sa.w * 64 + lane];
        uint v4 = Tb[(size_t)sb.x * 64 + lane];
        uint v5 = Tb[(size_t)sb.y * 64 + lane];
        uint v6 = Tb[(size_t)sb.z * 64 + lane];
        uint v7 = Tb[(size_t)sb.w * 64 + lane];
        acc0 += ((h_lo(v0) + h_lo(v1)) + (h_lo(v2) + h_lo(v3))) +
                ((h_lo(v4) + h_lo(v5)) + (h_lo(v6) + h_lo(v7)));
        acc1 += ((h_hi(v0) + h_hi(v1)) + (h_hi(v2) + h_hi(v3))) +
                ((h_hi(v4) + h_hi(v5)) + (h_hi(v6) + h_hi(v7)));
    }
    for (; j + 4 <= c; j += 4) {
        int4 s4 = *reinterpret_cast<const int4*>(row + j);
        uint v0 = Tb[(size_t)s4.x * 64 + lane];
        uint v1 = Tb[(size_t)s4.y * 64 + lane];
        uint v2 = Tb[(size_t)s4.z * 64 + lane];
        uint v3 = Tb[(size_t)s4.w * 64 + lane];
        acc0 += (h_lo(v0) + h_lo(v1)) + (h_lo(v2) + h_lo(v3));
        acc1 += (h_hi(v0) + h_hi(v1)) + (h_hi(v2) + h_hi(v3));
    }
    for (; j < c; ++j) {
        uint v = Tb[(size_t)row[j] * 64 + lane];
        acc0 += h_lo(v);
        acc1 += h_hi(v);
    }
    float2 bv = *reinterpret_cast<const float2*>(bias + lane * 2);
    float h0 = fmaxf(fmaf(di, acc0, bv.x), 0.f);
    float h1 = fmaxf(fmaf(di, acc1, bv.y), 0.f);
    float2 wv = *reinterpret_cast<const float2*>(Wout + lane * 2);
    float v = fmaf(h0, wv.x, h1 * wv.y);
#pragma unroll
    for (int off = 32; off > 0; off >>= 1) v += __shfl_xor(v, off, 64);
    if (lane == 0) out[gw] = 1.f / (1.f + expf(-(v + bout[0])));
}

extern "C" void kernel_launch(void* const* d_in, const int* in_sizes, int n_in,
                              void* d_out, int out_size, void* d_ws, size_t ws_size,
                              hipStream_t stream) {
    const float* x    = (const float*)d_in[0];
    const int*   ei   = (const int*)d_in[1];
    const float* W1   = (const float*)d_in[2];
    const float* b1   = (const float*)d_in[3];
    const float* W2   = (const float*)d_in[4];
    const float* b2   = (const float*)d_in[5];
    const float* Wout = (const float*)d_in[6];
    const float* bout = (const float*)d_in[7];
    float* out = (float*)d_out;

    const int N = in_sizes[0] / 128;
    const int E = in_sizes[1] / 2;
    const int* esrc = ei;
    const int* edst = ei + E;

    char* p = (char*)d_ws;
    auto alloc = [&](size_t bytes) {
        char* r = p;
        p += (bytes + 255) & ~(size_t)255;
        return (void*)r;
    };
    int*   cnt = (int*)  alloc((size_t)N * 4);
    float* isd = (float*)alloc((size_t)N * 4);
    int*   ell = (int*)  alloc((size_t)N * CAPD * 4);
    uint*  Tb  = (uint*) alloc((size_t)N * 64 * 4);   // N x 128 fp16
    uint*  Hb  = (uint*) alloc((size_t)N * 64 * 4);   // N x 128 fp16
    uint*  Wt1 = (uint*) alloc(8192 * 4);
    uint*  Wt2 = (uint*) alloc(8192 * 4);

    // Partition scratch aliases Tb+Hb (not live until gemm).
    const int nb  = (N + BSZ - 1) / BSZ;
    const int NB2 = (E + CHUNK - 1) / CHUNK;
    char* q = (char*)Tb;
    auto alloc2 = [&](size_t bytes) {
        char* r = q;
        q += (bytes + 255) & ~(size_t)255;
        return (void*)r;
    };
    unsigned* gSorted    = (unsigned*)alloc2((size_t)E * 4);
    int*      gHist      = (int*)     alloc2((size_t)nb * NB2 * 4);
    int*      gStart     = (int*)     alloc2((size_t)nb * NB2 * 4);
    int*      bucketTot  = (int*)     alloc2((size_t)nb * 4);
    int*      bucketBase = (int*)     alloc2((size_t)(nb + 1) * 4);

    p1_count  <<<NB2, 256, 0, stream>>>(edst, E, nb, gHist);
    p2a_scan  <<<nb,  256, 0, stream>>>(gHist, gStart, nb, NB2, bucketTot);
    p2b_scan  <<<1,   256, 0, stream>>>(bucketTot, nb, bucketBase);
    p3_scatter<<<NB2, 256, 0, stream>>>(esrc, edst, E, nb, gStart, bucketBase, gSorted);
    p4_build  <<<nb,  256, 0, stream>>>(gSorted, bucketBase, N, cnt, isd, ell);

    wtb_kernel<<<2, 256, 0, stream>>>(W1, W2, Wt1, Wt2);

    const int gblocks = (N + 127) / 128;
    // Layer 1: Tb = fp16(diag(isd)*(x@W1)) ; Hb = fp16(relu(isd*(Tb_self + sum Tb_src) + b1))
    gemm_mfma<<<gblocks, 256, 0, stream>>>(x, 0, Wt1, isd, Tb, N);
    agg_kernel<<<(N + 3) / 4, 256, 0, stream>>>(Tb, ell, cnt, isd, b1, Hb, N);
    // Layer 2 + fused head (agg reads only Tb; out written directly)
    gemm_mfma<<<gblocks, 256, 0, stream>>>(Hb, 1, Wt2, isd, Tb, N);
    agg_out_kernel<<<(N + 3) / 4, 256, 0, stream>>>(Tb, ell, cnt, isd, b2, Wout, bout, out, N);
}

// Round 11
// 229.046 us; speedup vs baseline: 2.2389x; 1.0196x over previous
//
#include <hip/hip_runtime.h>
#include <cstddef>

#define CAPD 64
#define BSZ 512      // nodes per bucket
#define BSH 9        // log2(BSZ)
#define CHUNK 8192   // edges per partition block

typedef unsigned int uint;
typedef unsigned short ushort;
typedef float f32x4 __attribute__((ext_vector_type(4)));
typedef _Float16 f16x8 __attribute__((ext_vector_type(8)));  // 8 fp16 = 4 VGPRs

// fp16 helpers: word = dimEven | dimOdd<<16
__device__ inline float h_lo(uint v) {
    union { ushort u; _Float16 h; } c; c.u = (ushort)(v & 0xFFFFu); return (float)c.h;
}
__device__ inline float h_hi(uint v) {
    union { ushort u; _Float16 h; } c; c.u = (ushort)(v >> 16); return (float)c.h;
}
__device__ inline ushort h_bits(float x) {
    union { _Float16 h; ushort u; } c; c.h = (_Float16)x; return c.u;
}
__device__ inline uint h_pack(float a, float b) {
    return (uint)h_bits(a) | ((uint)h_bits(b) << 16);
}

// ---------- p1 + W-prep fused: blocks [0,NB2) histogram, blocks NB2/NB2+1 transpose W ----------
__global__ __launch_bounds__(256) void p1w(const int* __restrict__ edst, int E,
                                           int nb, int NB2, int* __restrict__ gHist,
                                           const float* __restrict__ W1,
                                           const float* __restrict__ W2,
                                           uint* __restrict__ Wt1, uint* __restrict__ Wt2) {
    __shared__ float ws[128][129];  // 66KB; reused as hist[] for histogram blocks
    int bid = blockIdx.x, tid = threadIdx.x;
    if (bid < NB2) {
        int* hist = (int*)&ws[0][0];
        hist[tid] = 0;
        __syncthreads();
        int e0 = bid * CHUNK, e1 = min(E, e0 + CHUNK);
        for (int e = e0 + tid; e < e1; e += 256)
            atomicAdd(&hist[edst[e] >> BSH], 1);
        __syncthreads();
        for (int i = tid; i < nb; i += 256)
            gHist[bid * nb + i] = hist[i];
    } else {
        const float* W = (bid - NB2) ? W2 : W1;
        uint* O = (bid - NB2) ? Wt2 : Wt1;
#pragma unroll
        for (int j = 0; j < 16; ++j) {
            int q = tid + 256 * j;          // 4096 float4 chunks
            int k = q >> 5, c = (q & 31) * 4;
            float4 v = *reinterpret_cast<const float4*>(W + k * 128 + c);
            ws[k][c] = v.x; ws[k][c + 1] = v.y; ws[k][c + 2] = v.z; ws[k][c + 3] = v.w;
        }
        __syncthreads();
#pragma unroll
        for (int j = 0; j < 32; ++j) {
            int q = tid + 256 * j;          // 8192 words: [col][64 kwords]
            int ncol = q >> 6, kw = q & 63;
            O[q] = h_pack(ws[2 * kw][ncol], ws[2 * kw + 1][ncol]);
        }
    }
}

// p2a: one block per bucket b. Within-bucket prefix over chunks (NB2 <= 256).
__global__ __launch_bounds__(256) void p2a_scan(const int* __restrict__ gHist,
                                                int* __restrict__ gStart,
                                                int nb, int NB2,
                                                int* __restrict__ bucketTot) {
    __shared__ int sc[256];
    int b = blockIdx.x, t = threadIdx.x;
    int v = (t < NB2) ? gHist[t * nb + b] : 0;
    sc[t] = v;
    __syncthreads();
    for (int off = 1; off < 256; off <<= 1) {
        int u = (t >= off) ? sc[t - off] : 0;
        __syncthreads();
        sc[t] += u;
        __syncthreads();
    }
    if (t < NB2) gStart[t * nb + b] = sc[t] - v;
    if (t == 255) bucketTot[b] = sc[255];
}

// p3: single global pass. Stage dst+src in LDS, counting-sort, write bucket segments.
// bucketBase derived locally from bucketTot (196-int LDS scan).
__global__ __launch_bounds__(256) void p3_scatter(const int* __restrict__ esrc,
                                                  const int* __restrict__ edst, int E,
                                                  int nb,
                                                  const int* __restrict__ gStart,
                                                  const int* __restrict__ bucketTot,
                                                  unsigned* __restrict__ gSorted) {
    __shared__ unsigned dstL[CHUNK];   // 32KB
    __shared__ unsigned srcL[CHUNK];   // 32KB
    __shared__ unsigned outL[CHUNK];   // 32KB
    __shared__ int hist[256], segoff[256], cursor[256], gbase[256], sc[256];
    int bid = blockIdx.x, tid = threadIdx.x;
    int e0 = bid * CHUNK;
    int m = min(E - e0, CHUNK);
    for (int i = tid; i < m; i += 256) {
        dstL[i] = (unsigned)edst[e0 + i];
        srcL[i] = (unsigned)esrc[e0 + i];
    }
    hist[tid] = 0;
    __syncthreads();
    for (int i = tid; i < m; i += 256)
        atomicAdd(&hist[dstL[i] >> BSH], 1);
    __syncthreads();
    // scan 1: hist -> segoff/cursor
    sc[tid] = hist[tid];
    __syncthreads();
    for (int off = 1; off < 256; off <<= 1) {
        int v = (tid >= off) ? sc[tid - off] : 0;
        __syncthreads();
        sc[tid] += v;
        __syncthreads();
    }
    segoff[tid] = sc[tid] - hist[tid];
    cursor[tid] = segoff[tid];
    __syncthreads();
    // scan 2: bucketTot -> bucketBase; gbase = gStart + base
    int bt = (tid < nb) ? bucketTot[tid] : 0;
    sc[tid] = bt;
    __syncthreads();
    for (int off = 1; off < 256; off <<= 1) {
        int v = (tid >= off) ? sc[tid - off] : 0;
        __syncthreads();
        sc[tid] += v;
        __syncthreads();
    }
    if (tid < nb) gbase[tid] = gStart[bid * nb + tid] + (sc[tid] - bt);
    __syncthreads();
    for (int i = tid; i < m; i += 256) {
        unsigned d = dstL[i];
        int b = (int)(d >> BSH);
        int p = atomicAdd(&cursor[b], 1);
        outL[p] = srcL[i] | ((d & (BSZ - 1)) << 23);
    }
    __syncthreads();
    int wave = tid >> 6, lane = tid & 63;
    for (int b = wave; b < nb; b += 4) {
        int off = segoff[b], len = hist[b], gb = gbase[b];
        for (int i = lane; i < len; i += 64)
            gSorted[gb + i] = outL[off + i];
    }
}

// p4: one block per bucket. Build ELL in LDS; write only used entries (skip padding).
__global__ __launch_bounds__(256) void p4_build(const unsigned* __restrict__ gSorted,
                                                const int* __restrict__ bucketTot,
                                                int nb, int N, int* __restrict__ cnt,
                                                float* __restrict__ isd,
                                                int* __restrict__ ell) {
    __shared__ unsigned ellL[BSZ * CAPD];  // 128KB
    __shared__ int cntL[BSZ];
    __shared__ int sc[256];
    __shared__ int baseS, lenS;
    int b = blockIdx.x, tid = threadIdx.x;
    int n0 = b * BSZ;
    // derive base/len from bucketTot scan
    int bt = (tid < nb) ? bucketTot[tid] : 0;
    sc[tid] = bt;
    __syncthreads();
    for (int off = 1; off < 256; off <<= 1) {
        int u = (tid >= off) ? sc[tid - off] : 0;
        __syncthreads();
        sc[tid] += u;
        __syncthreads();
    }
    if (tid == b) { baseS = sc[b] - bt; lenS = bt; }
    for (int i = tid; i < BSZ; i += 256) cntL[i] = 0;
    __syncthreads();
    int base = baseS, len = lenS;
    for (int i = tid; i < len; i += 256) {
        unsigned e = gSorted[base + i];
        int dl = (int)(e >> 23);
        int src = (int)(e & 0x7FFFFFu);
        int p = atomicAdd(&cntL[dl], 1);
        if (p < CAPD) ellL[dl * CAPD + p] = (unsigned)src;
    }
    __syncthreads();
    int nValid = min(BSZ, N - n0);
    int total = nValid * CAPD;
    const int* ellLi = (const int*)ellL;
    for (int i = tid; i < total; i += 256) {
        int row = i >> 6, pos = i & 63;
        int c = cntL[row];
        if (pos < min(c, CAPD))
            ell[(size_t)n0 * CAPD + i] = ellLi[i];
    }
    for (int i = tid; i < nValid; i += 256) {
        int c = cntL[i];
        cnt[n0 + i] = c;
        isd[n0 + i] = rsqrtf(1.0f + (float)c);
    }
}

// ---------- fp16 MFMA GEMM: Tb = fp16( diag(scale) * (A @ W) ) ----------
// A: f32 [n][128] (aF16=0) or fp16-pair [n][64] (aF16=1). Wt: [128 cols][64 kwords] fp16.
// Block 128x128, 4 waves, LDS 64KB -> 2 blocks/CU.
// Swizzle: byte ^= ((row&7)<<4) kills the 256B-stride bank conflict (G4/T2).
__global__ __launch_bounds__(256) void gemm_mfma(const void* __restrict__ A, int aF16,
                                                 const uint* __restrict__ Wt,
                                                 const float* __restrict__ scale,
                                                 uint* __restrict__ Tb, int n) {
    __shared__ uint SH[16384];  // 64KB: A [0,32K), W [32K,64K); epilogue reuses
    char* shb = (char*)SH;
    const int tid = threadIdx.x;
    const int m0 = blockIdx.x * 128;

    if (aF16) {
        const uint* Af = (const uint*)A;
#pragma unroll
        for (int j = 0; j < 8; ++j) {
            int q = tid + 256 * j;
            int row = q >> 4, c16 = q & 15;
            int grow = m0 + row;
            uint4 v = make_uint4(0u, 0u, 0u, 0u);
            if (grow < n) v = *reinterpret_cast<const uint4*>(Af + (size_t)grow * 64 + c16 * 4);
            *reinterpret_cast<uint4*>(shb + row * 256 + ((c16 * 16) ^ ((row & 7) << 4))) = v;
        }
    } else {
        const float* Af = (const float*)A;
#pragma unroll
        for (int j = 0; j < 8; ++j) {
            int q = tid + 256 * j;
            int row = q >> 4, c16 = q & 15;
            int grow = m0 + row;
            uint4 o = make_uint4(0u, 0u, 0u, 0u);
            if (grow < n) {
                float4 v0 = *reinterpret_cast<const float4*>(Af + (size_t)grow * 128 + c16 * 8);
                float4 v1 = *reinterpret_cast<const float4*>(Af + (size_t)grow * 128 + c16 * 8 + 4);
                o.x = h_pack(v0.x, v0.y); o.y = h_pack(v0.z, v0.w);
                o.z = h_pack(v1.x, v1.y); o.w = h_pack(v1.z, v1.w);
            }
            *reinterpret_cast<uint4*>(shb + row * 256 + ((c16 * 16) ^ ((row & 7) << 4))) = o;
        }
    }
#pragma unroll
    for (int j = 0; j < 8; ++j) {
        int q = tid + 256 * j;
        int col = q >> 4, c16 = q & 15;
        uint4 v = *reinterpret_cast<const uint4*>(Wt + col * 64 + c16 * 4);
        *reinterpret_cast<uint4*>(shb + 32768 + col * 256 + ((c16 * 16) ^ ((col & 7) << 4))) = v;
    }
    __syncthreads();

    const int w = tid >> 6, l = tid & 63;
    const int lrow = l & 15, kg = l >> 4;
    const int swz = (lrow & 7) << 4;

    f32x4 acc[2][8] = {};
#pragma unroll
    for (int kk = 0; kk < 4; ++kk) {
        const int koff = (kk * 64 + kg * 16) ^ swz;
        f16x8 a[2], b[8];
#pragma unroll
        for (int mr = 0; mr < 2; ++mr) {
            int r = w * 32 + mr * 16 + lrow;
            a[mr] = *reinterpret_cast<const f16x8*>(shb + r * 256 + koff);
        }
#pragma unroll
        for (int nc = 0; nc < 8; ++nc) {
            int c = nc * 16 + lrow;
            b[nc] = *reinterpret_cast<const f16x8*>(shb + 32768 + c * 256 + koff);
        }
#pragma unroll
        for (int mr = 0; mr < 2; ++mr)
#pragma unroll
            for (int nc = 0; nc < 8; ++nc)
                acc[mr][nc] = __builtin_amdgcn_mfma_f32_16x16x32_f16(a[mr], b[nc], acc[mr][nc], 0, 0, 0);
    }
    __syncthreads();  // tiles consumed; reuse LDS for epilogue transpose

    // C/D layout (m89): col = lane&15, row = (lane>>4)*4 + reg. Scale + pack via LDS.
    ushort* Cs = (ushort*)SH;   // [128][136] fp16 (pad breaks bank alignment)
#pragma unroll
    for (int mr = 0; mr < 2; ++mr) {
        int rb = w * 32 + mr * 16 + kg * 4;
#pragma unroll
        for (int i = 0; i < 4; ++i) {
            int grow = m0 + rb + i;
            float s = (grow < n) ? scale[grow] : 0.f;
#pragma unroll
            for (int nc = 0; nc < 8; ++nc)
                Cs[(rb + i) * 136 + nc * 16 + lrow] = h_bits(s * acc[mr][nc][i]);
        }
    }
    __syncthreads();
    const uint* Cw = (const uint*)SH;             // stride 68 words/row
#pragma unroll
    for (int j = 0; j < 8; ++j) {
        int q = tid + 256 * j;
        int row = q >> 4, c4 = q & 15;
        int grow = m0 + row;
        if (grow < n) {
            uint4 v = *reinterpret_cast<const uint4*>(Cw + row * 68 + c4 * 4);
            *reinterpret_cast<uint4*>(Tb + (size_t)grow * 64 + c4 * 4) = v;
        }
    }
}

// ---------- aggregation (fp16 gather in, fp16 out) ----------
__global__ __launch_bounds__(256) void agg_kernel(const uint* __restrict__ Tb,
                                                  const int* __restrict__ ell,
                                                  const int* __restrict__ cnt,
                                                  const float* __restrict__ isd,
                                                  const float* __restrict__ bias,
                                                  uint* __restrict__ Hb, int n) {
    int gw = (int)((blockIdx.x * 256 + threadIdx.x) >> 6);
    int lane = threadIdx.x & 63;
    if (gw >= n) return;
    float di = isd[gw];
    int c = cnt[gw];
    if (c > CAPD) c = CAPD;
    const int* row = ell + (size_t)gw * CAPD;
    uint sv = Tb[(size_t)gw * 64 + lane];
    float acc0 = h_lo(sv), acc1 = h_hi(sv);
    int j = 0;
    for (; j + 8 <= c; j += 8) {
        int4 sa = *reinterpret_cast<const int4*>(row + j);
        int4 sb = *reinterpret_cast<const int4*>(row + j + 4);
        uint v0 = Tb[(size_t)sa.x * 64 + lane];
        uint v1 = Tb[(size_t)sa.y * 64 + lane];
        uint v2 = Tb[(size_t)sa.z * 64 + lane];
        uint v3 = Tb[(size_t)sa.w * 64 + lane];
        uint v4 = Tb[(size_t)sb.x * 64 + lane];
        uint v5 = Tb[(size_t)sb.y * 64 + lane];
        uint v6 = Tb[(size_t)sb.z * 64 + lane];
        uint v7 = Tb[(size_t)sb.w * 64 + lane];
        acc0 += ((h_lo(v0) + h_lo(v1)) + (h_lo(v2) + h_lo(v3))) +
                ((h_lo(v4) + h_lo(v5)) + (h_lo(v6) + h_lo(v7)));
        acc1 += ((h_hi(v0) + h_hi(v1)) + (h_hi(v2) + h_hi(v3))) +
                ((h_hi(v4) + h_hi(v5)) + (h_hi(v6) + h_hi(v7)));
    }
    for (; j + 4 <= c; j += 4) {
        int4 s4 = *reinterpret_cast<const int4*>(row + j);
        uint v0 = Tb[(size_t)s4.x * 64 + lane];
        uint v1 = Tb[(size_t)s4.y * 64 + lane];
        uint v2 = Tb[(size_t)s4.z * 64 + lane];
        uint v3 = Tb[(size_t)s4.w * 64 + lane];
        acc0 += (h_lo(v0) + h_lo(v1)) + (h_lo(v2) + h_lo(v3));
        acc1 += (h_hi(v0) + h_hi(v1)) + (h_hi(v2) + h_hi(v3));
    }
    for (; j < c; ++j) {
        uint v = Tb[(size_t)row[j] * 64 + lane];
        acc0 += h_lo(v);
        acc1 += h_hi(v);
    }
    float2 bv = *reinterpret_cast<const float2*>(bias + lane * 2);
    float h0 = fmaxf(fmaf(di, acc0, bv.x), 0.f);
    float h1 = fmaxf(fmaf(di, acc1, bv.y), 0.f);
    Hb[(size_t)gw * 64 + lane] = h_pack(h0, h1);
}

// ---------- layer-2 agg fused with output head ----------
__global__ __launch_bounds__(256) void agg_out_kernel(const uint* __restrict__ Tb,
                                                      const int* __restrict__ ell,
                                                      const int* __restrict__ cnt,
                                                      const float* __restrict__ isd,
                                                      const float* __restrict__ bias,
                                                      const float* __restrict__ Wout,
                                                      const float* __restrict__ bout,
                                                      float* __restrict__ out, int n) {
    int gw = (int)((blockIdx.x * 256 + threadIdx.x) >> 6);
    int lane = threadIdx.x & 63;
    if (gw >= n) return;
    float di = isd[gw];
    int c = cnt[gw];
    if (c > CAPD) c = CAPD;
    const int* row = ell + (size_t)gw * CAPD;
    uint sv = Tb[(size_t)gw * 64 + lane];
    float acc0 = h_lo(sv), acc1 = h_hi(sv);
    int j = 0;
    for (; j + 8 <= c; j += 8) {
        int4 sa = *reinterpret_cast<const int4*>(row + j);
        int4 sb = *reinterpret_cast<const int4*>(row + j + 4);
        uint v0 = Tb[(size_t)sa.x * 64 + lane];
        uint v1 = Tb[(size_t)sa.y * 64 + lane];
        uint v2 = Tb[(size_t)sa.z * 64 + lane];
        uint v3 = Tb[(size_t)sa.w * 64 + lane];
        uint v4 = Tb[(size_t)sb.x * 64 + lane];
        uint v5 = Tb[(size_t)sb.y * 64 + lane];
        uint v6 = Tb[(size_t)sb.z * 64 + lane];
        uint v7 = Tb[(size_t)sb.w * 64 + lane];
        acc0 += ((h_lo(v0) + h_lo(v1)) + (h_lo(v2) + h_lo(v3))) +
                ((h_lo(v4) + h_lo(v5)) + (h_lo(v6) + h_lo(v7)));
        acc1 += ((h_hi(v0) + h_hi(v1)) + (h_hi(v2) + h_hi(v3))) +
                ((h_hi(v4) + h_hi(v5)) + (h_hi(v6) + h_hi(v7)));
    }
    for (; j + 4 <= c; j += 4) {
        int4 s4 = *reinterpret_cast<const int4*>(row + j);
        uint v0 = Tb[(size_t)s4.x * 64 + lane];
        uint v1 = Tb[(size_t)s4.y * 64 + lane];
        uint v2 = Tb[(size_t)s4.z * 64 + lane];
        uint v3 = Tb[(size_t)s4.w * 64 + lane];
        acc0 += (h_lo(v0) + h_lo(v1)) + (h_lo(v2) + h_lo(v3));
        acc1 += (h_hi(v0) + h_hi(v1)) + (h_hi(v2) + h_hi(v3));
    }
    for (; j < c; ++j) {
        uint v = Tb[(size_t)row[j] * 64 + lane];
        acc0 += h_lo(v);
        acc1 += h_hi(v);
    }
    float2 bv = *reinterpret_cast<const float2*>(bias + lane * 2);
    float h0 = fmaxf(fmaf(di, acc0, bv.x), 0.f);
    float h1 = fmaxf(fmaf(di, acc1, bv.y), 0.f);
    float2 wv = *reinterpret_cast<const float2*>(Wout + lane * 2);
    float v = fmaf(h0, wv.x, h1 * wv.y);
#pragma unroll
    for (int off = 32; off > 0; off >>= 1) v += __shfl_xor(v, off, 64);
    if (lane == 0) out[gw] = 1.f / (1.f + expf(-(v + bout[0])));
}

extern "C" void kernel_launch(void* const* d_in, const int* in_sizes, int n_in,
                              void* d_out, int out_size, void* d_ws, size_t ws_size,
                              hipStream_t stream) {
    const float* x    = (const float*)d_in[0];
    const int*   ei   = (const int*)d_in[1];
    const float* W1   = (const float*)d_in[2];
    const float* b1   = (const float*)d_in[3];
    const float* W2   = (const float*)d_in[4];
    const float* b2   = (const float*)d_in[5];
    const float* Wout = (const float*)d_in[6];
    const float* bout = (const float*)d_in[7];
    float* out = (float*)d_out;

    const int N = in_sizes[0] / 128;
    const int E = in_sizes[1] / 2;
    const int* esrc = ei;
    const int* edst = ei + E;

    char* p = (char*)d_ws;
    auto alloc = [&](size_t bytes) {
        char* r = p;
        p += (bytes + 255) & ~(size_t)255;
        return (void*)r;
    };
    int*   cnt = (int*)  alloc((size_t)N * 4);
    float* isd = (float*)alloc((size_t)N * 4);
    int*   ell = (int*)  alloc((size_t)N * CAPD * 4);
    uint*  Tb  = (uint*) alloc((size_t)N * 64 * 4);   // N x 128 fp16
    uint*  Hb  = (uint*) alloc((size_t)N * 64 * 4);   // N x 128 fp16
    uint*  Wt1 = (uint*) alloc(8192 * 4);
    uint*  Wt2 = (uint*) alloc(8192 * 4);

    // Partition scratch aliases Tb+Hb (not live until gemm).
    const int nb  = (N + BSZ - 1) / BSZ;
    const int NB2 = (E + CHUNK - 1) / CHUNK;
    char* q = (char*)Tb;
    auto alloc2 = [&](size_t bytes) {
        char* r = q;
        q += (bytes + 255) & ~(size_t)255;
        return (void*)r;
    };
    unsigned* gSorted   = (unsigned*)alloc2((size_t)E * 4);
    int*      gHist     = (int*)     alloc2((size_t)nb * NB2 * 4);
    int*      gStart    = (int*)     alloc2((size_t)nb * NB2 * 4);
    int*      bucketTot = (int*)     alloc2((size_t)nb * 4);

    p1w       <<<NB2 + 2, 256, 0, stream>>>(edst, E, nb, NB2, gHist, W1, W2, Wt1, Wt2);
    p2a_scan  <<<nb,      256, 0, stream>>>(gHist, gStart, nb, NB2, bucketTot);
    p3_scatter<<<NB2,     256, 0, stream>>>(esrc, edst, E, nb, gStart, bucketTot, gSorted);
    p4_build  <<<nb,      256, 0, stream>>>(gSorted, bucketTot, nb, N, cnt, isd, ell);

    const int gblocks = (N + 127) / 128;
    // Layer 1: Tb = fp16(diag(isd)*(x@W1)) ; Hb = fp16(relu(isd*(Tb_self + sum Tb_src) + b1))
    gemm_mfma<<<gblocks, 256, 0, stream>>>(x, 0, Wt1, isd, Tb, N);
    agg_kernel<<<(N + 3) / 4, 256, 0, stream>>>(Tb, ell, cnt, isd, b1, Hb, N);
    // Layer 2 + fused head (agg reads only Tb; out written directly)
    gemm_mfma<<<gblocks, 256, 0, stream>>>(Hb, 1, Wt2, isd, Tb, N);
    agg_out_kernel<<<(N + 3) / 4, 256, 0, stream>>>(Tb, ell, cnt, isd, b2, Wout, bout, out, N);
}